// Round 2
// baseline (1215.241 us; speedup 1.0000x reference)
//
#include <hip/hip_runtime.h>
#include <stdint.h>

#define NND 40000
#define NE  640000
#define NG  128
#define DIM 128
#define HID 64
#define ADJ_BLOCKS 640
#define NOISY_BLOCKS 5000   // NND*32/256

// ---------------- threefry2x32 (20 rounds), JAX-compatible ----------------
__host__ __device__ inline uint32_t rotl32(uint32_t v, uint32_t r) {
    return (v << r) | (v >> (32u - r));
}

__host__ __device__ inline void threefry2x32(uint32_t k0, uint32_t k1,
                                             uint32_t& x0, uint32_t& x1) {
    uint32_t k2 = k0 ^ k1 ^ 0x1BD11BDAu;
    x0 += k0; x1 += k1;
#define TFR(r) { x0 += x1; x1 = rotl32(x1, r); x1 ^= x0; }
    TFR(13u) TFR(15u) TFR(26u) TFR(6u)
    x0 += k1; x1 += k2 + 1u;
    TFR(17u) TFR(29u) TFR(16u) TFR(24u)
    x0 += k2; x1 += k0 + 2u;
    TFR(13u) TFR(15u) TFR(26u) TFR(6u)
    x0 += k0; x1 += k1 + 3u;
    TFR(17u) TFR(29u) TFR(16u) TFR(24u)
    x0 += k1; x1 += k2 + 4u;
    TFR(13u) TFR(15u) TFR(26u) TFR(6u)
    x0 += k2; x1 += k0 + 5u;
#undef TFR
}

// partitionable-mode random bits -> uniform [0,1)
__device__ inline float rbits_u01(uint32_t k0, uint32_t k1, uint32_t idx) {
    uint32_t x0 = 0u, x1 = idx;
    threefry2x32(k0, k1, x0, x1);
    uint32_t b = x0 ^ x1;
    return __uint_as_float((b >> 9) | 0x3f800000u) - 1.0f;
}

// ---------------- CSR build ----------------
__global__ __launch_bounds__(256) void hist_kernel(const int* __restrict__ dst,
                                                   int* __restrict__ deg) {
    int e = blockIdx.x * 256 + threadIdx.x;
    if (e < NE) atomicAdd(&deg[dst[e]], 1);
}

__global__ __launch_bounds__(1024) void scan_kernel(const int* __restrict__ deg,
                                                    int* __restrict__ offv,
                                                    int* __restrict__ cursor) {
    __shared__ int ps[1024];
    int t = threadIdx.x;
    const int CH = (NND + 1023) / 1024; // 40
    int base = t * CH;
    int s = 0;
    for (int i = 0; i < CH; i++) { int idx = base + i; if (idx < NND) s += deg[idx]; }
    ps[t] = s;
    __syncthreads();
    for (int d = 1; d < 1024; d <<= 1) {
        int v = (t >= d) ? ps[t - d] : 0;
        __syncthreads();
        ps[t] += v;
        __syncthreads();
    }
    if (t == 1023) offv[NND] = ps[1023];
    int run = (t == 0) ? 0 : ps[t - 1];
    for (int i = 0; i < CH; i++) {
        int idx = base + i;
        if (idx < NND) { offv[idx] = run; cursor[idx] = run; run += deg[idx]; }
    }
}

__global__ __launch_bounds__(256) void build_kernel(const int* __restrict__ src,
                                                    const int* __restrict__ dst,
                                                    int* __restrict__ cursor,
                                                    int* __restrict__ elist) {
    int e = blockIdx.x * 256 + threadIdx.x;
    if (e < NE) {
        int p = atomicAdd(&cursor[dst[e]], 1);
        elist[p] = src[e];
    }
}

// agg[n] = sum over in-edges of feat[src]; full overwrite (no zero-init needed)
__global__ __launch_bounds__(256) void gather_kernel(const float* __restrict__ feat,
                                                     const int* __restrict__ offv,
                                                     const int* __restrict__ elist,
                                                     float* __restrict__ agg) {
    int gt = blockIdx.x * 256 + threadIdx.x;
    int n = gt >> 5, c4 = gt & 31;
    int o0 = offv[n], o1 = offv[n + 1];
    float4 acc = make_float4(0.f, 0.f, 0.f, 0.f);
    for (int i = o0; i < o1; i++) {
        int s = elist[i];
        float4 v = *(const float4*)(feat + (size_t)s * DIM + c4 * 4);
        acc.x += v.x; acc.y += v.y; acc.z += v.z; acc.w += v.w;
    }
    *(float4*)(agg + (size_t)n * DIM + c4 * 4) = acc;
}

// ---------------- fused GEMM: out = ACT((A [+ A2]) @ W [+ bias]); optional col stats
// ACT: 0=none, 1=relu, 2=tanh.  STATS: write per-block col sum/sumsq partials to sscr.
template <int K, int M, int ACT, int STATS>
__global__ __launch_bounds__(256) void gemm_kernel(const float* __restrict__ A,
                                                   const float* A2,
                                                   const float* __restrict__ W,
                                                   const float* __restrict__ bias,
                                                   float* out,
                                                   float* __restrict__ sscr,
                                                   int nrows) {
    constexpr int CG  = M / 8;        // column groups (8 cols each)
    constexpr int RG  = 256 / CG;     // row groups
    constexpr int RPB = RG * 4;       // rows per block
    constexpr int KP  = K + 4;        // padded LDS row stride
    __shared__ __align__(16) float sW[K * M];
    __shared__ __align__(16) float sS[RPB * KP];

    const int t = threadIdx.x;
    const int row0 = blockIdx.x * RPB;

    for (int i = t; i < (K * M) / 4; i += 256)
        ((float4*)sW)[i] = ((const float4*)W)[i];

    for (int i = t; i < (RPB * K) / 4; i += 256) {
        int r = i / (K / 4), k4 = i % (K / 4);
        int gr = row0 + r;
        float4 v = make_float4(0.f, 0.f, 0.f, 0.f);
        if (gr < nrows) {
            v = ((const float4*)(A + (size_t)gr * K))[k4];
            if (A2) {
                float4 w2 = ((const float4*)(A2 + (size_t)gr * K))[k4];
                v.x += w2.x; v.y += w2.y; v.z += w2.z; v.w += w2.w;
            }
        }
        *(float4*)(sS + r * KP + k4 * 4) = v;
    }
    __syncthreads();

    const int cg = t % CG, rg = t / CG;
    float acc[4][8];
#pragma unroll
    for (int i = 0; i < 4; i++)
#pragma unroll
        for (int j = 0; j < 8; j++) acc[i][j] = 0.f;

    const float* sSr = sS + (rg * 4) * KP;
    const float4* sW4 = (const float4*)sW;
#pragma unroll 4
    for (int k = 0; k < K; k++) {
        float4 wA = sW4[k * (M / 4) + cg * 2];
        float4 wB = sW4[k * (M / 4) + cg * 2 + 1];
        float wv[8] = {wA.x, wA.y, wA.z, wA.w, wB.x, wB.y, wB.z, wB.w};
        float sv[4] = {sSr[k], sSr[KP + k], sSr[2 * KP + k], sSr[3 * KP + k]};
#pragma unroll
        for (int i = 0; i < 4; i++)
#pragma unroll
            for (int j = 0; j < 8; j++) acc[i][j] = fmaf(sv[i], wv[j], acc[i][j]);
    }

    float bv[8];
#pragma unroll
    for (int j = 0; j < 8; j++) bv[j] = bias ? bias[cg * 8 + j] : 0.f;

    float ps[8], pq[8];
#pragma unroll
    for (int j = 0; j < 8; j++) { ps[j] = 0.f; pq[j] = 0.f; }

#pragma unroll
    for (int i = 0; i < 4; i++) {
        int gr = row0 + rg * 4 + i;
        if (gr < nrows) {
            float o[8];
#pragma unroll
            for (int j = 0; j < 8; j++) {
                float v = acc[i][j] + bv[j];
                if (ACT == 1) v = fmaxf(v, 0.f);
                if (ACT == 2) v = tanhf(v);
                o[j] = v;
                ps[j] += v; pq[j] += v * v;
            }
            float4* o4 = (float4*)(out + (size_t)gr * M + cg * 8);
            o4[0] = make_float4(o[0], o[1], o[2], o[3]);
            o4[1] = make_float4(o[4], o[5], o[6], o[7]);
        }
    }

    if (STATS) {
        __syncthreads();  // done reading sS; reuse as reduction scratch
#pragma unroll
        for (int j = 0; j < 8; j++) {
            sS[rg * M + cg * 8 + j] = ps[j];
            sS[RG * M + rg * M + cg * 8 + j] = pq[j];
        }
        __syncthreads();
        if (t < M) {
            float s = 0.f, q = 0.f;
#pragma unroll
            for (int i = 0; i < RG; i++) { s += sS[i * M + t]; q += sS[RG * M + i * M + t]; }
            sscr[(size_t)blockIdx.x * 2 * M + t]     = s;
            sscr[(size_t)blockIdx.x * 2 * M + M + t] = q;
        }
    }
}

// reduce per-block stats partials -> cs[2M]; launch <<<1, 2*M>>>
template <int M>
__global__ void stats_reduce_kernel(const float* __restrict__ sscr, int nblk,
                                    float* __restrict__ cs) {
    int t = threadIdx.x;   // [0, 2M)
    float s = 0.f;
    for (int b = 0; b < nblk; b++) s += sscr[(size_t)b * 2 * M + t];
    cs[t] = s;
}

// ---------------- in-place batchnorm apply (stats finalized inline) ----------------
template <int NC, int RELU>
__global__ __launch_bounds__(256) void bn_apply_kernel(float* buf,
                                                       const float* __restrict__ cs,
                                                       const float* __restrict__ g,
                                                       const float* __restrict__ b) {
    int i = blockIdx.x * 256 + threadIdx.x;
    const int total4 = NND * NC / 4;
    if (i >= total4) return;
    int c = (i * 4) % NC;
    const float invN = 1.0f / (float)NND;
    float4 v = ((float4*)buf)[i];
    float o[4] = {v.x, v.y, v.z, v.w};
#pragma unroll
    for (int j = 0; j < 4; j++) {
        float mu = cs[c + j] * invN;
        float var = fmaxf(cs[NC + c + j] * invN - mu * mu, 0.f);
        float rs = rsqrtf(var + 1e-5f);
        float A = g[c + j] * rs;
        float B = b[c + j] - mu * A;
        float y = fmaf(o[j], A, B);
        if (RELU) y = fmaxf(y, 0.f);
        o[j] = y;
    }
    ((float4*)buf)[i] = make_float4(o[0], o[1], o[2], o[3]);
}

// ---------------- assignment / gumbel-softmax lambdas ----------------
__global__ __launch_bounds__(256) void assign_kernel(const float* __restrict__ a1,
                                                     const float* __restrict__ Wfc2,
                                                     const float* __restrict__ bfc2,
                                                     float* __restrict__ assn,
                                                     float* __restrict__ lam,
                                                     uint32_t kg0, uint32_t kg1) {
    __shared__ float w[DIM * 2];
    int t = threadIdx.x;
    w[t] = Wfc2[t];  // 256 threads, 256 values
    __syncthreads();
    int n = blockIdx.x * 256 + t;
    if (n >= NND) return;

    float d0 = bfc2[0], d1 = bfc2[1];
    const float4* row4 = (const float4*)(a1 + (size_t)n * DIM);
#pragma unroll 8
    for (int k4 = 0; k4 < DIM / 4; k4++) {
        float4 v = row4[k4];
        d0 = fmaf(v.x, w[8 * k4 + 0], d0); d1 = fmaf(v.x, w[8 * k4 + 1], d1);
        d0 = fmaf(v.y, w[8 * k4 + 2], d0); d1 = fmaf(v.y, w[8 * k4 + 3], d1);
        d0 = fmaf(v.z, w[8 * k4 + 4], d0); d1 = fmaf(v.z, w[8 * k4 + 5], d1);
        d0 = fmaf(v.w, w[8 * k4 + 6], d0); d1 = fmaf(v.w, w[8 * k4 + 7], d1);
    }
    float m = fmaxf(d0, d1);
    float e0 = expf(d0 - m), e1 = expf(d1 - m);
    float inv = 1.f / (e0 + e1);
    float as0 = e0 * inv, as1 = e1 * inv;
    assn[2 * n] = as0; assn[2 * n + 1] = as1;

    float uf0 = rbits_u01(kg0, kg1, (uint32_t)(2 * n));
    float uf1 = rbits_u01(kg0, kg1, (uint32_t)(2 * n + 1));
    float u0 = fmaxf(1e-10f, uf0 + 1e-10f);
    float u1 = fmaxf(1e-10f, uf1 + 1e-10f);
    float gu0 = -logf(-logf(u0));
    float gu1 = -logf(-logf(u1));
    float y0 = as0 + gu0, y1 = as1 + gu1;
    float mm = fmaxf(y0, y1);
    float f0 = expf(y0 - mm), f1 = expf(y1 - mm);
    float iv = 1.f / (f0 + f1);
    lam[2 * n] = f0 * iv; lam[2 * n + 1] = f1 * iv;
}

// ---------------- noisy features + kl partial sums (per-block, no atomics) ------
__global__ __launch_bounds__(256) void noisy_kernel(const float* __restrict__ nfeat,
                                                    const float* __restrict__ lam,
                                                    const float* __restrict__ cs3,
                                                    float* __restrict__ noisy,
                                                    float* __restrict__ kpart,
                                                    uint32_t kn0, uint32_t kn1) {
    int gt = blockIdx.x * 256 + threadIdx.x;
    int n = gt >> 5, c4 = gt & 31, d = c4 * 4;
    const float invN = 1.0f / (float)NND;
    float la0 = lam[2 * n], la1 = lam[2 * n + 1];
    float4 xv = *(const float4*)(nfeat + (size_t)n * DIM + d);
    float xa[4] = {xv.x, xv.y, xv.z, xv.w};
    float t1 = 0.f, t2 = 0.f, o[4];
#pragma unroll
    for (int j = 0; j < 4; j++) {
        float mu = cs3[d + j] * invN;
        float q = cs3[DIM + d + j];
        float var1 = fmaxf(q - (float)NND * mu * mu, 0.f) / (float)(NND - 1);
        float sd = sqrtf(var1);
        float r = rbits_u01(kn0, kn1, (uint32_t)(n * DIM + d + j));
        float nm = la0 * xa[j] + la1 * mu;
        float ns = la1 * sd;
        o[j] = fmaf(r, ns, nm);
        float inv = 1.0f / (sd + 1e-7f);
        float z1 = ns * inv;            t1 += z1 * z1;
        float z2 = (nm - mu) * inv;     t2 += z2 * z2;
    }
    *(float4*)(noisy + (size_t)n * DIM + d) = make_float4(o[0], o[1], o[2], o[3]);

    __shared__ float s1[256], s2[256];
    int t = threadIdx.x;
    s1[t] = t1; s2[t] = t2;
    __syncthreads();
    for (int s = 128; s > 0; s >>= 1) {
        if (t < s) { s1[t] += s1[t + s]; s2[t] += s2[t + s]; }
        __syncthreads();
    }
    if (t == 0) { kpart[2 * blockIdx.x] = s1[0]; kpart[2 * blockIdx.x + 1] = s2[0]; }
}

// ---------------- graph segment starts (batch is sorted) ----------------
__global__ __launch_bounds__(256) void gstart_kernel(const int* __restrict__ batch,
                                                     int* __restrict__ gstart) {
    int i = blockIdx.x * 256 + threadIdx.x;
    if (i >= NND) return;
    int b = batch[i];
    int prev = (i == 0) ? -1 : batch[i - 1];
    for (int g = prev + 1; g <= b; g++) gstart[g] = i;
    if (i == NND - 1)
        for (int g = b + 1; g <= NG; g++) gstart[g] = NND;
}

__global__ __launch_bounds__(128) void graph_emb_kernel(const float* __restrict__ noisy,
                                                        const int* __restrict__ gstart,
                                                        float* __restrict__ emb) {
    int g = blockIdx.x, c = threadIdx.x;
    int s = gstart[g], e = gstart[g + 1];
    float acc = 0.f;
    for (int r = s; r < e; r++) acc += noisy[(size_t)r * DIM + c];
    float cnt = (float)(e - s);
    emb[(size_t)g * DIM + c] = acc / fmaxf(cnt, 1.f);
}

// ---------------- proto distances + final head (one wave per graph) ----------------
__global__ __launch_bounds__(64) void head_kernel(const float* __restrict__ emb,
                                                  const float* __restrict__ protos,
                                                  const float* __restrict__ Wlast,
                                                  float* __restrict__ out_logits,
                                                  float* __restrict__ out_probs,
                                                  float* __restrict__ out_sim,
                                                  float* __restrict__ out_dist) {
    int g = blockIdx.x, l = threadIdx.x;
    float ge0 = emb[(size_t)g * DIM + l];
    float ge1 = emb[(size_t)g * DIM + l + 64];
    float gn = ge0 * ge0 + ge1 * ge1;
    float dj[10], pj[10];
#pragma unroll
    for (int j = 0; j < 10; j++) {
        float pa = protos[j * DIM + l], pb = protos[j * DIM + l + 64];
        dj[j] = ge0 * pa + ge1 * pb;
        pj[j] = pa * pa + pb * pb;
    }
    float wl0 = ge0 * Wlast[10 + l] + ge1 * Wlast[10 + l + 64];
    float wl1 = ge0 * Wlast[138 + 10 + l] + ge1 * Wlast[138 + 10 + l + 64];
#pragma unroll
    for (int s = 32; s > 0; s >>= 1) {
        gn += __shfl_xor(gn, s);
        wl0 += __shfl_xor(wl0, s);
        wl1 += __shfl_xor(wl1, s);
#pragma unroll
        for (int j = 0; j < 10; j++) {
            dj[j] += __shfl_xor(dj[j], s);
            pj[j] += __shfl_xor(pj[j], s);
        }
    }
    if (l == 0) {
        float lg0 = wl0, lg1 = wl1;
#pragma unroll
        for (int j = 0; j < 10; j++) {
            float dist = -2.f * dj[j] + gn + pj[j];
            float sv = logf((dist + 1.0f) / (dist + 1e-4f));
            out_dist[g * 10 + j] = dist;
            out_sim[g * 10 + j] = sv;
            lg0 = fmaf(Wlast[j], sv, lg0);
            lg1 = fmaf(Wlast[138 + j], sv, lg1);
        }
        out_logits[2 * g] = lg0; out_logits[2 * g + 1] = lg1;
        float m = fmaxf(lg0, lg1);
        float e0 = expf(lg0 - m), e1 = expf(lg1 - m);
        float iv = 1.f / (e0 + e1);
        out_probs[2 * g] = e0 * iv; out_probs[2 * g + 1] = e1 * iv;
    }
}

// ---------------- 2x2 adjacency accumulation (per-block partials) ----------------
__global__ __launch_bounds__(256) void adj_kernel(const float* __restrict__ assn,
                                                  const int* __restrict__ src,
                                                  const int* __restrict__ dst,
                                                  float* __restrict__ adjp) {
    int t = threadIdx.x;
    float p00 = 0.f, p01 = 0.f, p10 = 0.f, p11 = 0.f;
    for (int e = blockIdx.x * 256 + t; e < NE; e += ADJ_BLOCKS * 256) {
        float2 a = *(const float2*)(assn + 2 * (size_t)src[e]);
        float2 b = *(const float2*)(assn + 2 * (size_t)dst[e]);
        p00 += a.x * b.x; p01 += a.x * b.y; p10 += a.y * b.x; p11 += a.y * b.y;
    }
    __shared__ float s0[256], s1[256], s2[256], s3[256];
    s0[t] = p00; s1[t] = p01; s2[t] = p10; s3[t] = p11;
    __syncthreads();
    for (int s = 128; s > 0; s >>= 1) {
        if (t < s) { s0[t] += s0[t + s]; s1[t] += s1[t + s]; s2[t] += s2[t + s]; s3[t] += s3[t + s]; }
        __syncthreads();
    }
    if (t == 0) {
        float4* o = (float4*)(adjp + 4 * (size_t)blockIdx.x);
        *o = make_float4(s0[0], s1[0], s2[0], s3[0]);
    }
}

// ---------------- final scalars: reduce kl + adj partials ----------------
__global__ __launch_bounds__(256) void final_scalar_kernel(const float* __restrict__ kpart,
                                                           const float* __restrict__ adjp,
                                                           float* __restrict__ out) {
    __shared__ float sh[6 * 256];
    int t = threadIdx.x;
    float k1 = 0.f, k2 = 0.f, a0 = 0.f, a1 = 0.f, a2 = 0.f, a3 = 0.f;
    for (int i = t; i < NOISY_BLOCKS; i += 256) {
        float2 v = ((const float2*)kpart)[i];
        k1 += v.x; k2 += v.y;
    }
    for (int i = t; i < ADJ_BLOCKS; i += 256) {
        float4 v = ((const float4*)adjp)[i];
        a0 += v.x; a1 += v.y; a2 += v.z; a3 += v.w;
    }
    sh[t] = k1; sh[256 + t] = k2; sh[512 + t] = a0;
    sh[768 + t] = a1; sh[1024 + t] = a2; sh[1280 + t] = a3;
    __syncthreads();
    for (int s = 128; s > 0; s >>= 1) {
        if (t < s) {
#pragma unroll
            for (int v = 0; v < 6; v++) sh[v * 256 + t] += sh[v * 256 + t + s];
        }
        __syncthreads();
    }
    if (t == 0) {
        float kl = 0.5f / ((float)NND * (float)DIM) * sh[0] + (1.0f / (float)DIM) * sh[256];
        out[16896] = kl;
        float a00 = sh[512], a01 = sh[768], a10 = sh[1024], a11 = sh[1280];
        float r0 = fmaxf(fabsf(a00) + fabsf(a01), 1e-12f);
        float r1 = fmaxf(fabsf(a10) + fabsf(a11), 1e-12f);
        float d0 = a00 / r0 - 1.f, d1 = a11 / r1 - 1.f;
        out[16897] = 0.5f * (d0 * d0 + d1 * d1);
    }
}

// ---------------- launcher ----------------
extern "C" void kernel_launch(void* const* d_in, const int* in_sizes, int n_in,
                              void* d_out, int out_size, void* d_ws, size_t ws_size,
                              hipStream_t stream) {
    (void)in_sizes; (void)n_in; (void)out_size; (void)ws_size;
    const float* x     = (const float*)d_in[0];
    const int*   ei    = (const int*)d_in[1];
    const int*   batch = (const int*)d_in[2];
    const float* W0a   = (const float*)d_in[3];
    const float* W0b   = (const float*)d_in[4];
    const float* g0    = (const float*)d_in[5];
    const float* b0    = (const float*)d_in[6];
    const float* W1a   = (const float*)d_in[7];
    const float* W1b   = (const float*)d_in[8];
    const float* g1    = (const float*)d_in[9];
    const float* b1    = (const float*)d_in[10];
    const float* Wm0   = (const float*)d_in[11];
    const float* bm0   = (const float*)d_in[12];
    const float* gm    = (const float*)d_in[13];
    const float* bm    = (const float*)d_in[14];
    const float* Wm1   = (const float*)d_in[15];
    const float* bm1   = (const float*)d_in[16];
    const float* Wfc1  = (const float*)d_in[17];
    const float* bfc1  = (const float*)d_in[18];
    const float* Wfc2  = (const float*)d_in[19];
    const float* bfc2  = (const float*)d_in[20];
    const float* protos= (const float*)d_in[21];
    const float* Wlast = (const float*)d_in[22];
    const int* src = ei;
    const int* dst = ei + NE;
    float* out = (float*)d_out;

    float* ws   = (float*)d_ws;
    float* agg  = ws;                               // N*128
    float* tA   = agg + (size_t)NND * DIM;          // N*128
    float* t5   = tA + (size_t)NND * DIM;           // N*64
    float* lam  = t5 + (size_t)NND * HID;           // N*2
    float* assn = lam + (size_t)NND * 2;            // N*2
    float* cs   = assn + (size_t)NND * 2;           // 1024 (4 stat segments)
    float* kpart= cs + 1024;                        // NOISY_BLOCKS*2
    float* adjp = kpart + NOISY_BLOCKS * 2;         // ADJ_BLOCKS*4
    float* sscr = adjp + ADJ_BLOCKS * 4;            // 625*256 stats partials
    int* ib     = (int*)(sscr + 625 * 256);         // int region
    int* deg    = ib;                               // N
    int* offv   = deg + NND;                        // N+1
    int* cursor = offv + NND + 1;                   // N
    int* elist  = cursor + NND;                     // E
    int* gstart = elist + NE;                       // NG+1

    // threefry keys on host: key(42) = (0,42); partitionable fold-like split
    uint32_t kg0 = 0u, kg1 = 0u; threefry2x32(0u, 42u, kg0, kg1);  // ctr (0,0)
    uint32_t kn0 = 0u, kn1 = 1u; threefry2x32(0u, 42u, kn0, kn1);  // ctr (0,1)

    hipMemsetAsync(deg, 0, NND * sizeof(int), stream);

    // CSR (shared by both GIN layers)
    hist_kernel<<<(NE + 255) / 256, 256, 0, stream>>>(dst, deg);
    scan_kernel<<<1, 1024, 0, stream>>>(deg, offv, cursor);
    build_kernel<<<(NE + 255) / 256, 256, 0, stream>>>(src, dst, cursor, elist);

    // GIN layer 1
    gather_kernel<<<(NND * 32) / 256, 256, 0, stream>>>(x, offv, elist, agg);
    gemm_kernel<128,128,1,0><<<625, 256, 0, stream>>>(x, agg, W0a, nullptr, agg, nullptr, NND);
    gemm_kernel<128,128,1,1><<<625, 256, 0, stream>>>(agg, nullptr, W0b, nullptr, tA, sscr, NND);
    stats_reduce_kernel<128><<<1, 256, 0, stream>>>(sscr, 625, cs + 0);
    bn_apply_kernel<128,1><<<5000, 256, 0, stream>>>(tA, cs + 0, g0, b0);      // nf1

    // GIN layer 2
    gather_kernel<<<(NND * 32) / 256, 256, 0, stream>>>(tA, offv, elist, agg);
    gemm_kernel<128,128,1,0><<<625, 256, 0, stream>>>(tA, agg, W1a, nullptr, agg, nullptr, NND);
    gemm_kernel<128,128,1,1><<<625, 256, 0, stream>>>(agg, nullptr, W1b, nullptr, tA, sscr, NND);
    stats_reduce_kernel<128><<<1, 256, 0, stream>>>(sscr, 625, cs + 256);
    bn_apply_kernel<128,0><<<5000, 256, 0, stream>>>(tA, cs + 256, g1, b1);    // nf2

    // bottleneck MLP
    gemm_kernel<128,64,0,1><<<313, 256, 0, stream>>>(tA, nullptr, Wm0, bm0, t5, sscr, NND);
    stats_reduce_kernel<64><<<1, 128, 0, stream>>>(sscr, 313, cs + 512);
    bn_apply_kernel<64,1><<<2500, 256, 0, stream>>>(t5, cs + 512, gm, bm);     // h
    gemm_kernel<64,128,0,1><<<625, 256, 0, stream>>>(t5, nullptr, Wm1, bm1, agg, sscr, NND); // node_feature
    stats_reduce_kernel<128><<<1, 256, 0, stream>>>(sscr, 625, cs + 640);
    gemm_kernel<128,128,2,0><<<625, 256, 0, stream>>>(agg, nullptr, Wfc1, bfc1, tA, nullptr, NND); // a1

    // assignment + gumbel
    assign_kernel<<<(NND + 255) / 256, 256, 0, stream>>>(tA, Wfc2, bfc2, assn, lam, kg0, kg1);

    // noisy features (into tA) + kl partials
    noisy_kernel<<<NOISY_BLOCKS, 256, 0, stream>>>(agg, lam, cs + 640, tA, kpart, kn0, kn1);

    // graph pooling + head
    gstart_kernel<<<(NND + 255) / 256, 256, 0, stream>>>(batch, gstart);
    graph_emb_kernel<<<NG, 128, 0, stream>>>(tA, gstart, out + 512);
    head_kernel<<<NG, 64, 0, stream>>>(out + 512, protos, Wlast,
                                       out, out + 256, out + 16898, out + 18178);

    // penalties
    adj_kernel<<<ADJ_BLOCKS, 256, 0, stream>>>(assn, src, dst, adjp);
    final_scalar_kernel<<<1, 256, 0, stream>>>(kpart, adjp, out);
}

// Round 3
// 718.305 us; speedup vs baseline: 1.6918x; 1.6918x over previous
//
#include <hip/hip_runtime.h>
#include <stdint.h>

#define NND 40000
#define NE  640000
#define NG  128
#define DIM 128
#define HID 64
#define ADJ_BLOCKS 640
#define NOISY_BLOCKS 5000   // NND*32/256

// ---------------- threefry2x32 (20 rounds), JAX-compatible ----------------
__host__ __device__ inline uint32_t rotl32(uint32_t v, uint32_t r) {
    return (v << r) | (v >> (32u - r));
}

__host__ __device__ inline void threefry2x32(uint32_t k0, uint32_t k1,
                                             uint32_t& x0, uint32_t& x1) {
    uint32_t k2 = k0 ^ k1 ^ 0x1BD11BDAu;
    x0 += k0; x1 += k1;
#define TFR(r) { x0 += x1; x1 = rotl32(x1, r); x1 ^= x0; }
    TFR(13u) TFR(15u) TFR(26u) TFR(6u)
    x0 += k1; x1 += k2 + 1u;
    TFR(17u) TFR(29u) TFR(16u) TFR(24u)
    x0 += k2; x1 += k0 + 2u;
    TFR(13u) TFR(15u) TFR(26u) TFR(6u)
    x0 += k0; x1 += k1 + 3u;
    TFR(17u) TFR(29u) TFR(16u) TFR(24u)
    x0 += k1; x1 += k2 + 4u;
    TFR(13u) TFR(15u) TFR(26u) TFR(6u)
    x0 += k2; x1 += k0 + 5u;
#undef TFR
}

// partitionable-mode random bits -> uniform [0,1)
__device__ inline float rbits_u01(uint32_t k0, uint32_t k1, uint32_t idx) {
    uint32_t x0 = 0u, x1 = idx;
    threefry2x32(k0, k1, x0, x1);
    uint32_t b = x0 ^ x1;
    return __uint_as_float((b >> 9) | 0x3f800000u) - 1.0f;
}

// ---------------- CSR build ----------------
__global__ __launch_bounds__(256) void hist_kernel(const int* __restrict__ dst,
                                                   int* __restrict__ deg) {
    int e = blockIdx.x * 256 + threadIdx.x;
    if (e < NE) atomicAdd(&deg[dst[e]], 1);
}

__global__ __launch_bounds__(1024) void scan_kernel(const int* __restrict__ deg,
                                                    int* __restrict__ offv,
                                                    int* __restrict__ cursor) {
    __shared__ int ps[1024];
    int t = threadIdx.x;
    const int CH = (NND + 1023) / 1024; // 40
    int base = t * CH;
    int s = 0;
    for (int i = 0; i < CH; i++) { int idx = base + i; if (idx < NND) s += deg[idx]; }
    ps[t] = s;
    __syncthreads();
    for (int d = 1; d < 1024; d <<= 1) {
        int v = (t >= d) ? ps[t - d] : 0;
        __syncthreads();
        ps[t] += v;
        __syncthreads();
    }
    if (t == 1023) offv[NND] = ps[1023];
    int run = (t == 0) ? 0 : ps[t - 1];
    for (int i = 0; i < CH; i++) {
        int idx = base + i;
        if (idx < NND) { offv[idx] = run; cursor[idx] = run; run += deg[idx]; }
    }
}

__global__ __launch_bounds__(256) void build_kernel(const int* __restrict__ src,
                                                    const int* __restrict__ dst,
                                                    int* __restrict__ cursor,
                                                    int* __restrict__ elist) {
    int e = blockIdx.x * 256 + threadIdx.x;
    if (e < NE) {
        int p = atomicAdd(&cursor[dst[e]], 1);
        elist[p] = src[e];
    }
}

// agg[n] = sum over in-edges of feat[src]; full overwrite (no zero-init needed)
__global__ __launch_bounds__(256) void gather_kernel(const float* __restrict__ feat,
                                                     const int* __restrict__ offv,
                                                     const int* __restrict__ elist,
                                                     float* __restrict__ agg) {
    int gt = blockIdx.x * 256 + threadIdx.x;
    int n = gt >> 5, c4 = gt & 31;
    int o0 = offv[n], o1 = offv[n + 1];
    float4 acc = make_float4(0.f, 0.f, 0.f, 0.f);
    for (int i = o0; i < o1; i++) {
        int s = elist[i];
        float4 v = *(const float4*)(feat + (size_t)s * DIM + c4 * 4);
        acc.x += v.x; acc.y += v.y; acc.z += v.z; acc.w += v.w;
    }
    *(float4*)(agg + (size_t)n * DIM + c4 * 4) = acc;
}

// ---------------- fused GEMM: out = ACT((A [+ A2]) @ W [+ bias]); optional col stats
// ACT: 0=none, 1=relu, 2=tanh.  STATS: write per-block col sum/sumsq partials to sscr.
template <int K, int M, int ACT, int STATS>
__global__ __launch_bounds__(256) void gemm_kernel(const float* __restrict__ A,
                                                   const float* A2,
                                                   const float* __restrict__ W,
                                                   const float* __restrict__ bias,
                                                   float* out,
                                                   float* __restrict__ sscr,
                                                   int nrows) {
    constexpr int CG  = M / 8;        // column groups (8 cols each)
    constexpr int RG  = 256 / CG;     // row groups
    constexpr int RPB = RG * 4;       // rows per block
    constexpr int KP  = K + 4;        // padded LDS row stride
    __shared__ __align__(16) float sW[K * M];
    __shared__ __align__(16) float sS[RPB * KP];

    const int t = threadIdx.x;
    const int row0 = blockIdx.x * RPB;

    for (int i = t; i < (K * M) / 4; i += 256)
        ((float4*)sW)[i] = ((const float4*)W)[i];

    for (int i = t; i < (RPB * K) / 4; i += 256) {
        int r = i / (K / 4), k4 = i % (K / 4);
        int gr = row0 + r;
        float4 v = make_float4(0.f, 0.f, 0.f, 0.f);
        if (gr < nrows) {
            v = ((const float4*)(A + (size_t)gr * K))[k4];
            if (A2) {
                float4 w2 = ((const float4*)(A2 + (size_t)gr * K))[k4];
                v.x += w2.x; v.y += w2.y; v.z += w2.z; v.w += w2.w;
            }
        }
        *(float4*)(sS + r * KP + k4 * 4) = v;
    }
    __syncthreads();

    const int cg = t % CG, rg = t / CG;
    float acc[4][8];
#pragma unroll
    for (int i = 0; i < 4; i++)
#pragma unroll
        for (int j = 0; j < 8; j++) acc[i][j] = 0.f;

    const float* sSr = sS + (rg * 4) * KP;
    const float4* sW4 = (const float4*)sW;
#pragma unroll 4
    for (int k = 0; k < K; k++) {
        float4 wA = sW4[k * (M / 4) + cg * 2];
        float4 wB = sW4[k * (M / 4) + cg * 2 + 1];
        float wv[8] = {wA.x, wA.y, wA.z, wA.w, wB.x, wB.y, wB.z, wB.w};
        float sv[4] = {sSr[k], sSr[KP + k], sSr[2 * KP + k], sSr[3 * KP + k]};
#pragma unroll
        for (int i = 0; i < 4; i++)
#pragma unroll
            for (int j = 0; j < 8; j++) acc[i][j] = fmaf(sv[i], wv[j], acc[i][j]);
    }

    float bv[8];
#pragma unroll
    for (int j = 0; j < 8; j++) bv[j] = bias ? bias[cg * 8 + j] : 0.f;

    float ps[8], pq[8];
#pragma unroll
    for (int j = 0; j < 8; j++) { ps[j] = 0.f; pq[j] = 0.f; }

#pragma unroll
    for (int i = 0; i < 4; i++) {
        int gr = row0 + rg * 4 + i;
        if (gr < nrows) {
            float o[8];
#pragma unroll
            for (int j = 0; j < 8; j++) {
                float v = acc[i][j] + bv[j];
                if (ACT == 1) v = fmaxf(v, 0.f);
                if (ACT == 2) v = tanhf(v);
                o[j] = v;
                ps[j] += v; pq[j] += v * v;
            }
            float4* o4 = (float4*)(out + (size_t)gr * M + cg * 8);
            o4[0] = make_float4(o[0], o[1], o[2], o[3]);
            o4[1] = make_float4(o[4], o[5], o[6], o[7]);
        }
    }

    if (STATS) {
        __syncthreads();  // done reading sS; reuse as reduction scratch
#pragma unroll
        for (int j = 0; j < 8; j++) {
            sS[rg * M + cg * 8 + j] = ps[j];
            sS[RG * M + rg * M + cg * 8 + j] = pq[j];
        }
        __syncthreads();
        if (t < M) {
            float s = 0.f, q = 0.f;
#pragma unroll
            for (int i = 0; i < RG; i++) { s += sS[i * M + t]; q += sS[RG * M + i * M + t]; }
            sscr[(size_t)blockIdx.x * 2 * M + t]     = s;
            sscr[(size_t)blockIdx.x * 2 * M + M + t] = q;
        }
    }
}

// parallel reduce: sscr[nblk][2M] -> cs[2M]; grid = 2M/8 blocks x 256 threads.
// Each block owns 8 columns; 32 row-lanes stride over nblk rows; LDS tree across lanes.
template <int M>
__global__ __launch_bounds__(256) void stats_reduce_kernel(const float* __restrict__ sscr,
                                                           int nblk,
                                                           float* __restrict__ cs) {
    const int cols = 2 * M;
    const int t = threadIdx.x;
    const int c = blockIdx.x * 8 + (t & 7);   // global column
    const int rl = t >> 3;                    // row lane 0..31
    float s = 0.f;
    for (int r = rl; r < nblk; r += 32)
        s += sscr[(size_t)r * cols + c];
    __shared__ float sh[256];
    sh[t] = s;
    __syncthreads();
#pragma unroll
    for (int st = 128; st >= 8; st >>= 1) {
        if (t < st) sh[t] += sh[t + st];
        __syncthreads();
    }
    if (t < 8) cs[c] = sh[t];
}

// ---------------- in-place batchnorm apply (stats finalized inline) ----------------
template <int NC, int RELU>
__global__ __launch_bounds__(256) void bn_apply_kernel(float* buf,
                                                       const float* __restrict__ cs,
                                                       const float* __restrict__ g,
                                                       const float* __restrict__ b) {
    int i = blockIdx.x * 256 + threadIdx.x;
    const int total4 = NND * NC / 4;
    if (i >= total4) return;
    int c = (i * 4) % NC;
    const float invN = 1.0f / (float)NND;
    float4 v = ((float4*)buf)[i];
    float o[4] = {v.x, v.y, v.z, v.w};
#pragma unroll
    for (int j = 0; j < 4; j++) {
        float mu = cs[c + j] * invN;
        float var = fmaxf(cs[NC + c + j] * invN - mu * mu, 0.f);
        float rs = rsqrtf(var + 1e-5f);
        float A = g[c + j] * rs;
        float B = b[c + j] - mu * A;
        float y = fmaf(o[j], A, B);
        if (RELU) y = fmaxf(y, 0.f);
        o[j] = y;
    }
    ((float4*)buf)[i] = make_float4(o[0], o[1], o[2], o[3]);
}

// ---------------- assignment / gumbel-softmax lambdas ----------------
__global__ __launch_bounds__(256) void assign_kernel(const float* __restrict__ a1,
                                                     const float* __restrict__ Wfc2,
                                                     const float* __restrict__ bfc2,
                                                     float* __restrict__ assn,
                                                     float* __restrict__ lam,
                                                     uint32_t kg0, uint32_t kg1) {
    __shared__ float w[DIM * 2];
    int t = threadIdx.x;
    w[t] = Wfc2[t];  // 256 threads, 256 values
    __syncthreads();
    int n = blockIdx.x * 256 + t;
    if (n >= NND) return;

    float d0 = bfc2[0], d1 = bfc2[1];
    const float4* row4 = (const float4*)(a1 + (size_t)n * DIM);
#pragma unroll 8
    for (int k4 = 0; k4 < DIM / 4; k4++) {
        float4 v = row4[k4];
        d0 = fmaf(v.x, w[8 * k4 + 0], d0); d1 = fmaf(v.x, w[8 * k4 + 1], d1);
        d0 = fmaf(v.y, w[8 * k4 + 2], d0); d1 = fmaf(v.y, w[8 * k4 + 3], d1);
        d0 = fmaf(v.z, w[8 * k4 + 4], d0); d1 = fmaf(v.z, w[8 * k4 + 5], d1);
        d0 = fmaf(v.w, w[8 * k4 + 6], d0); d1 = fmaf(v.w, w[8 * k4 + 7], d1);
    }
    float m = fmaxf(d0, d1);
    float e0 = expf(d0 - m), e1 = expf(d1 - m);
    float inv = 1.f / (e0 + e1);
    float as0 = e0 * inv, as1 = e1 * inv;
    assn[2 * n] = as0; assn[2 * n + 1] = as1;

    float uf0 = rbits_u01(kg0, kg1, (uint32_t)(2 * n));
    float uf1 = rbits_u01(kg0, kg1, (uint32_t)(2 * n + 1));
    float u0 = fmaxf(1e-10f, uf0 + 1e-10f);
    float u1 = fmaxf(1e-10f, uf1 + 1e-10f);
    float gu0 = -logf(-logf(u0));
    float gu1 = -logf(-logf(u1));
    float y0 = as0 + gu0, y1 = as1 + gu1;
    float mm = fmaxf(y0, y1);
    float f0 = expf(y0 - mm), f1 = expf(y1 - mm);
    float iv = 1.f / (f0 + f1);
    lam[2 * n] = f0 * iv; lam[2 * n + 1] = f1 * iv;
}

// ---------------- noisy features + kl partial sums (per-block, no atomics) ------
__global__ __launch_bounds__(256) void noisy_kernel(const float* __restrict__ nfeat,
                                                    const float* __restrict__ lam,
                                                    const float* __restrict__ cs3,
                                                    float* __restrict__ noisy,
                                                    float* __restrict__ kpart,
                                                    uint32_t kn0, uint32_t kn1) {
    int gt = blockIdx.x * 256 + threadIdx.x;
    int n = gt >> 5, c4 = gt & 31, d = c4 * 4;
    const float invN = 1.0f / (float)NND;
    float la0 = lam[2 * n], la1 = lam[2 * n + 1];
    float4 xv = *(const float4*)(nfeat + (size_t)n * DIM + d);
    float xa[4] = {xv.x, xv.y, xv.z, xv.w};
    float t1 = 0.f, t2 = 0.f, o[4];
#pragma unroll
    for (int j = 0; j < 4; j++) {
        float mu = cs3[d + j] * invN;
        float q = cs3[DIM + d + j];
        float var1 = fmaxf(q - (float)NND * mu * mu, 0.f) / (float)(NND - 1);
        float sd = sqrtf(var1);
        float r = rbits_u01(kn0, kn1, (uint32_t)(n * DIM + d + j));
        float nm = la0 * xa[j] + la1 * mu;
        float ns = la1 * sd;
        o[j] = fmaf(r, ns, nm);
        float inv = 1.0f / (sd + 1e-7f);
        float z1 = ns * inv;            t1 += z1 * z1;
        float z2 = (nm - mu) * inv;     t2 += z2 * z2;
    }
    *(float4*)(noisy + (size_t)n * DIM + d) = make_float4(o[0], o[1], o[2], o[3]);

    __shared__ float s1[256], s2[256];
    int t = threadIdx.x;
    s1[t] = t1; s2[t] = t2;
    __syncthreads();
    for (int s = 128; s > 0; s >>= 1) {
        if (t < s) { s1[t] += s1[t + s]; s2[t] += s2[t + s]; }
        __syncthreads();
    }
    if (t == 0) { kpart[2 * blockIdx.x] = s1[0]; kpart[2 * blockIdx.x + 1] = s2[0]; }
}

// ---------------- graph segment starts (batch is sorted) ----------------
__global__ __launch_bounds__(256) void gstart_kernel(const int* __restrict__ batch,
                                                     int* __restrict__ gstart) {
    int i = blockIdx.x * 256 + threadIdx.x;
    if (i >= NND) return;
    int b = batch[i];
    int prev = (i == 0) ? -1 : batch[i - 1];
    for (int g = prev + 1; g <= b; g++) gstart[g] = i;
    if (i == NND - 1)
        for (int g = b + 1; g <= NG; g++) gstart[g] = NND;
}

__global__ __launch_bounds__(128) void graph_emb_kernel(const float* __restrict__ noisy,
                                                        const int* __restrict__ gstart,
                                                        float* __restrict__ emb) {
    int g = blockIdx.x, c = threadIdx.x;
    int s = gstart[g], e = gstart[g + 1];
    float acc = 0.f;
    for (int r = s; r < e; r++) acc += noisy[(size_t)r * DIM + c];
    float cnt = (float)(e - s);
    emb[(size_t)g * DIM + c] = acc / fmaxf(cnt, 1.f);
}

// ---------------- proto distances + final head (one wave per graph) ----------------
__global__ __launch_bounds__(64) void head_kernel(const float* __restrict__ emb,
                                                  const float* __restrict__ protos,
                                                  const float* __restrict__ Wlast,
                                                  float* __restrict__ out_logits,
                                                  float* __restrict__ out_probs,
                                                  float* __restrict__ out_sim,
                                                  float* __restrict__ out_dist) {
    int g = blockIdx.x, l = threadIdx.x;
    float ge0 = emb[(size_t)g * DIM + l];
    float ge1 = emb[(size_t)g * DIM + l + 64];
    float gn = ge0 * ge0 + ge1 * ge1;
    float dj[10], pj[10];
#pragma unroll
    for (int j = 0; j < 10; j++) {
        float pa = protos[j * DIM + l], pb = protos[j * DIM + l + 64];
        dj[j] = ge0 * pa + ge1 * pb;
        pj[j] = pa * pa + pb * pb;
    }
    float wl0 = ge0 * Wlast[10 + l] + ge1 * Wlast[10 + l + 64];
    float wl1 = ge0 * Wlast[138 + 10 + l] + ge1 * Wlast[138 + 10 + l + 64];
#pragma unroll
    for (int s = 32; s > 0; s >>= 1) {
        gn += __shfl_xor(gn, s);
        wl0 += __shfl_xor(wl0, s);
        wl1 += __shfl_xor(wl1, s);
#pragma unroll
        for (int j = 0; j < 10; j++) {
            dj[j] += __shfl_xor(dj[j], s);
            pj[j] += __shfl_xor(pj[j], s);
        }
    }
    if (l == 0) {
        float lg0 = wl0, lg1 = wl1;
#pragma unroll
        for (int j = 0; j < 10; j++) {
            float dist = -2.f * dj[j] + gn + pj[j];
            float sv = logf((dist + 1.0f) / (dist + 1e-4f));
            out_dist[g * 10 + j] = dist;
            out_sim[g * 10 + j] = sv;
            lg0 = fmaf(Wlast[j], sv, lg0);
            lg1 = fmaf(Wlast[138 + j], sv, lg1);
        }
        out_logits[2 * g] = lg0; out_logits[2 * g + 1] = lg1;
        float m = fmaxf(lg0, lg1);
        float e0 = expf(lg0 - m), e1 = expf(lg1 - m);
        float iv = 1.f / (e0 + e1);
        out_probs[2 * g] = e0 * iv; out_probs[2 * g + 1] = e1 * iv;
    }
}

// ---------------- 2x2 adjacency accumulation (per-block partials) ----------------
__global__ __launch_bounds__(256) void adj_kernel(const float* __restrict__ assn,
                                                  const int* __restrict__ src,
                                                  const int* __restrict__ dst,
                                                  float* __restrict__ adjp) {
    int t = threadIdx.x;
    float p00 = 0.f, p01 = 0.f, p10 = 0.f, p11 = 0.f;
    for (int e = blockIdx.x * 256 + t; e < NE; e += ADJ_BLOCKS * 256) {
        float2 a = *(const float2*)(assn + 2 * (size_t)src[e]);
        float2 b = *(const float2*)(assn + 2 * (size_t)dst[e]);
        p00 += a.x * b.x; p01 += a.x * b.y; p10 += a.y * b.x; p11 += a.y * b.y;
    }
    __shared__ float s0[256], s1[256], s2[256], s3[256];
    s0[t] = p00; s1[t] = p01; s2[t] = p10; s3[t] = p11;
    __syncthreads();
    for (int s = 128; s > 0; s >>= 1) {
        if (t < s) { s0[t] += s0[t + s]; s1[t] += s1[t + s]; s2[t] += s2[t + s]; s3[t] += s3[t + s]; }
        __syncthreads();
    }
    if (t == 0) {
        float4* o = (float4*)(adjp + 4 * (size_t)blockIdx.x);
        *o = make_float4(s0[0], s1[0], s2[0], s3[0]);
    }
}

// ---------------- final scalars: reduce kl + adj partials ----------------
__global__ __launch_bounds__(256) void final_scalar_kernel(const float* __restrict__ kpart,
                                                           const float* __restrict__ adjp,
                                                           float* __restrict__ out) {
    __shared__ float sh[6 * 256];
    int t = threadIdx.x;
    float k1 = 0.f, k2 = 0.f, a0 = 0.f, a1 = 0.f, a2 = 0.f, a3 = 0.f;
    for (int i = t; i < NOISY_BLOCKS; i += 256) {
        float2 v = ((const float2*)kpart)[i];
        k1 += v.x; k2 += v.y;
    }
    for (int i = t; i < ADJ_BLOCKS; i += 256) {
        float4 v = ((const float4*)adjp)[i];
        a0 += v.x; a1 += v.y; a2 += v.z; a3 += v.w;
    }
    sh[t] = k1; sh[256 + t] = k2; sh[512 + t] = a0;
    sh[768 + t] = a1; sh[1024 + t] = a2; sh[1280 + t] = a3;
    __syncthreads();
    for (int s = 128; s > 0; s >>= 1) {
        if (t < s) {
#pragma unroll
            for (int v = 0; v < 6; v++) sh[v * 256 + t] += sh[v * 256 + t + s];
        }
        __syncthreads();
    }
    if (t == 0) {
        float kl = 0.5f / ((float)NND * (float)DIM) * sh[0] + (1.0f / (float)DIM) * sh[256];
        out[16896] = kl;
        float a00 = sh[512], a01 = sh[768], a10 = sh[1024], a11 = sh[1280];
        float r0 = fmaxf(fabsf(a00) + fabsf(a01), 1e-12f);
        float r1 = fmaxf(fabsf(a10) + fabsf(a11), 1e-12f);
        float d0 = a00 / r0 - 1.f, d1 = a11 / r1 - 1.f;
        out[16897] = 0.5f * (d0 * d0 + d1 * d1);
    }
}

// ---------------- launcher ----------------
extern "C" void kernel_launch(void* const* d_in, const int* in_sizes, int n_in,
                              void* d_out, int out_size, void* d_ws, size_t ws_size,
                              hipStream_t stream) {
    (void)in_sizes; (void)n_in; (void)out_size; (void)ws_size;
    const float* x     = (const float*)d_in[0];
    const int*   ei    = (const int*)d_in[1];
    const int*   batch = (const int*)d_in[2];
    const float* W0a   = (const float*)d_in[3];
    const float* W0b   = (const float*)d_in[4];
    const float* g0    = (const float*)d_in[5];
    const float* b0    = (const float*)d_in[6];
    const float* W1a   = (const float*)d_in[7];
    const float* W1b   = (const float*)d_in[8];
    const float* g1    = (const float*)d_in[9];
    const float* b1    = (const float*)d_in[10];
    const float* Wm0   = (const float*)d_in[11];
    const float* bm0   = (const float*)d_in[12];
    const float* gm    = (const float*)d_in[13];
    const float* bm    = (const float*)d_in[14];
    const float* Wm1   = (const float*)d_in[15];
    const float* bm1   = (const float*)d_in[16];
    const float* Wfc1  = (const float*)d_in[17];
    const float* bfc1  = (const float*)d_in[18];
    const float* Wfc2  = (const float*)d_in[19];
    const float* bfc2  = (const float*)d_in[20];
    const float* protos= (const float*)d_in[21];
    const float* Wlast = (const float*)d_in[22];
    const int* src = ei;
    const int* dst = ei + NE;
    float* out = (float*)d_out;

    float* ws   = (float*)d_ws;
    float* agg  = ws;                               // N*128
    float* tA   = agg + (size_t)NND * DIM;          // N*128
    float* t5   = tA + (size_t)NND * DIM;           // N*64
    float* lam  = t5 + (size_t)NND * HID;           // N*2
    float* assn = lam + (size_t)NND * 2;            // N*2
    float* cs   = assn + (size_t)NND * 2;           // 1024 (4 stat segments)
    float* kpart= cs + 1024;                        // NOISY_BLOCKS*2
    float* adjp = kpart + NOISY_BLOCKS * 2;         // ADJ_BLOCKS*4
    float* sscr = adjp + ADJ_BLOCKS * 4;            // 625*256 stats partials
    int* ib     = (int*)(sscr + 625 * 256);         // int region
    int* deg    = ib;                               // N
    int* offv   = deg + NND;                        // N+1
    int* cursor = offv + NND + 1;                   // N
    int* elist  = cursor + NND;                     // E
    int* gstart = elist + NE;                       // NG+1

    // threefry keys on host: key(42) = (0,42); partitionable fold-like split
    uint32_t kg0 = 0u, kg1 = 0u; threefry2x32(0u, 42u, kg0, kg1);  // ctr (0,0)
    uint32_t kn0 = 0u, kn1 = 1u; threefry2x32(0u, 42u, kn0, kn1);  // ctr (0,1)

    hipMemsetAsync(deg, 0, NND * sizeof(int), stream);

    // CSR (shared by both GIN layers)
    hist_kernel<<<(NE + 255) / 256, 256, 0, stream>>>(dst, deg);
    scan_kernel<<<1, 1024, 0, stream>>>(deg, offv, cursor);
    build_kernel<<<(NE + 255) / 256, 256, 0, stream>>>(src, dst, cursor, elist);

    // GIN layer 1
    gather_kernel<<<(NND * 32) / 256, 256, 0, stream>>>(x, offv, elist, agg);
    gemm_kernel<128,128,1,0><<<625, 256, 0, stream>>>(x, agg, W0a, nullptr, agg, nullptr, NND);
    gemm_kernel<128,128,1,1><<<625, 256, 0, stream>>>(agg, nullptr, W0b, nullptr, tA, sscr, NND);
    stats_reduce_kernel<128><<<32, 256, 0, stream>>>(sscr, 625, cs + 0);
    bn_apply_kernel<128,1><<<5000, 256, 0, stream>>>(tA, cs + 0, g0, b0);      // nf1

    // GIN layer 2
    gather_kernel<<<(NND * 32) / 256, 256, 0, stream>>>(tA, offv, elist, agg);
    gemm_kernel<128,128,1,0><<<625, 256, 0, stream>>>(tA, agg, W1a, nullptr, agg, nullptr, NND);
    gemm_kernel<128,128,1,1><<<625, 256, 0, stream>>>(agg, nullptr, W1b, nullptr, tA, sscr, NND);
    stats_reduce_kernel<128><<<32, 256, 0, stream>>>(sscr, 625, cs + 256);
    bn_apply_kernel<128,0><<<5000, 256, 0, stream>>>(tA, cs + 256, g1, b1);    // nf2

    // bottleneck MLP
    gemm_kernel<128,64,0,1><<<313, 256, 0, stream>>>(tA, nullptr, Wm0, bm0, t5, sscr, NND);
    stats_reduce_kernel<64><<<16, 256, 0, stream>>>(sscr, 313, cs + 512);
    bn_apply_kernel<64,1><<<2500, 256, 0, stream>>>(t5, cs + 512, gm, bm);     // h
    gemm_kernel<64,128,0,1><<<625, 256, 0, stream>>>(t5, nullptr, Wm1, bm1, agg, sscr, NND); // node_feature
    stats_reduce_kernel<128><<<32, 256, 0, stream>>>(sscr, 625, cs + 640);
    gemm_kernel<128,128,2,0><<<625, 256, 0, stream>>>(agg, nullptr, Wfc1, bfc1, tA, nullptr, NND); // a1

    // assignment + gumbel
    assign_kernel<<<(NND + 255) / 256, 256, 0, stream>>>(tA, Wfc2, bfc2, assn, lam, kg0, kg1);

    // noisy features (into tA) + kl partials
    noisy_kernel<<<NOISY_BLOCKS, 256, 0, stream>>>(agg, lam, cs + 640, tA, kpart, kn0, kn1);

    // graph pooling + head
    gstart_kernel<<<(NND + 255) / 256, 256, 0, stream>>>(batch, gstart);
    graph_emb_kernel<<<NG, 128, 0, stream>>>(tA, gstart, out + 512);
    head_kernel<<<NG, 64, 0, stream>>>(out + 512, protos, Wlast,
                                       out, out + 256, out + 16898, out + 18178);

    // penalties
    adj_kernel<<<ADJ_BLOCKS, 256, 0, stream>>>(assn, src, dst, adjp);
    final_scalar_kernel<<<1, 256, 0, stream>>>(kpart, adjp, out);
}

// Round 4
// 632.571 us; speedup vs baseline: 1.9211x; 1.1355x over previous
//
#include <hip/hip_runtime.h>
#include <stdint.h>

#define NND 40000
#define NE  640000
#define NG  128
#define DIM 128
#define HID 64
#define ADJ_BLOCKS 640
#define NOISY_BLOCKS 5000   // NND*32/256
#define NSCB ((NND + 255) / 256)   // 157 scan blocks

// ---------------- threefry2x32 (20 rounds), JAX-compatible ----------------
__host__ __device__ inline uint32_t rotl32(uint32_t v, uint32_t r) {
    return (v << r) | (v >> (32u - r));
}

__host__ __device__ inline void threefry2x32(uint32_t k0, uint32_t k1,
                                             uint32_t& x0, uint32_t& x1) {
    uint32_t k2 = k0 ^ k1 ^ 0x1BD11BDAu;
    x0 += k0; x1 += k1;
#define TFR(r) { x0 += x1; x1 = rotl32(x1, r); x1 ^= x0; }
    TFR(13u) TFR(15u) TFR(26u) TFR(6u)
    x0 += k1; x1 += k2 + 1u;
    TFR(17u) TFR(29u) TFR(16u) TFR(24u)
    x0 += k2; x1 += k0 + 2u;
    TFR(13u) TFR(15u) TFR(26u) TFR(6u)
    x0 += k0; x1 += k1 + 3u;
    TFR(17u) TFR(29u) TFR(16u) TFR(24u)
    x0 += k1; x1 += k2 + 4u;
    TFR(13u) TFR(15u) TFR(26u) TFR(6u)
    x0 += k2; x1 += k0 + 5u;
#undef TFR
}

// partitionable-mode random bits -> uniform [0,1)
__device__ inline float rbits_u01(uint32_t k0, uint32_t k1, uint32_t idx) {
    uint32_t x0 = 0u, x1 = idx;
    threefry2x32(k0, k1, x0, x1);
    uint32_t b = x0 ^ x1;
    return __uint_as_float((b >> 9) | 0x3f800000u) - 1.0f;
}

// ---------------- CSR build ----------------
__global__ __launch_bounds__(256) void hist_kernel(const int* __restrict__ dst,
                                                   int* __restrict__ deg) {
    int e = blockIdx.x * 256 + threadIdx.x;
    if (e < NE) atomicAdd(&deg[dst[e]], 1);
}

// hierarchical scan, step 1: per-block sums (coalesced)
__global__ __launch_bounds__(256) void scan_bsum_kernel(const int* __restrict__ deg,
                                                        int* __restrict__ bsum) {
    int t = threadIdx.x;
    int i = blockIdx.x * 256 + t;
    int v = (i < NND) ? deg[i] : 0;
    __shared__ int sh[256];
    sh[t] = v;
    __syncthreads();
#pragma unroll
    for (int s = 128; s > 0; s >>= 1) {
        if (t < s) sh[t] += sh[t + s];
        __syncthreads();
    }
    if (t == 0) bsum[blockIdx.x] = sh[0];
}

// step 2: single small block scans the 157 block sums -> exclusive block offsets
__global__ __launch_bounds__(256) void scan_boff_kernel(const int* __restrict__ bsum,
                                                        int* __restrict__ boff,
                                                        int* __restrict__ offv) {
    int t = threadIdx.x;
    int v = (t < NSCB) ? bsum[t] : 0;
    __shared__ int sh[256];
    sh[t] = v;
    __syncthreads();
    for (int d = 1; d < 256; d <<= 1) {
        int u = (t >= d) ? sh[t - d] : 0;
        __syncthreads();
        sh[t] += u;
        __syncthreads();
    }
    if (t < NSCB) boff[t] = sh[t] - v;   // exclusive
    if (t == NSCB - 1) offv[NND] = sh[t];
}

// step 3: block-local exclusive scan + block offset -> offv/cursor (coalesced)
__global__ __launch_bounds__(256) void scan_final_kernel(const int* __restrict__ deg,
                                                         const int* __restrict__ boff,
                                                         int* __restrict__ offv,
                                                         int* __restrict__ cursor) {
    int t = threadIdx.x;
    int i = blockIdx.x * 256 + t;
    int v = (i < NND) ? deg[i] : 0;
    __shared__ int sh[256];
    sh[t] = v;
    __syncthreads();
    for (int d = 1; d < 256; d <<= 1) {
        int u = (t >= d) ? sh[t - d] : 0;
        __syncthreads();
        sh[t] += u;
        __syncthreads();
    }
    int off = boff[blockIdx.x] + sh[t] - v;   // exclusive prefix
    if (i < NND) { offv[i] = off; cursor[i] = off; }
}

__global__ __launch_bounds__(256) void build_kernel(const int* __restrict__ src,
                                                    const int* __restrict__ dst,
                                                    int* __restrict__ cursor,
                                                    int* __restrict__ elist) {
    int e = blockIdx.x * 256 + threadIdx.x;
    if (e < NE) {
        int p = atomicAdd(&cursor[dst[e]], 1);
        elist[p] = src[e];
    }
}

// agg[n] = sum over in-edges of feat[src]; full overwrite (no zero-init needed)
__global__ __launch_bounds__(256) void gather_kernel(const float* __restrict__ feat,
                                                     const int* __restrict__ offv,
                                                     const int* __restrict__ elist,
                                                     float* __restrict__ agg) {
    int gt = blockIdx.x * 256 + threadIdx.x;
    int n = gt >> 5, c4 = gt & 31;
    int o0 = offv[n], o1 = offv[n + 1];
    float4 acc = make_float4(0.f, 0.f, 0.f, 0.f);
    for (int i = o0; i < o1; i++) {
        int s = elist[i];
        float4 v = *(const float4*)(feat + (size_t)s * DIM + c4 * 4);
        acc.x += v.x; acc.y += v.y; acc.z += v.z; acc.w += v.w;
    }
    *(float4*)(agg + (size_t)n * DIM + c4 * 4) = acc;
}

// ---------------- fused GEMM: out = ACT((A [+ A2]) @ W [+ bias]); optional col stats
// ACT: 0=none, 1=relu, 2=tanh.  STATS: write per-block col sum/sumsq partials to sscr.
template <int K, int M, int ACT, int STATS>
__global__ __launch_bounds__(256) void gemm_kernel(const float* __restrict__ A,
                                                   const float* A2,
                                                   const float* __restrict__ W,
                                                   const float* __restrict__ bias,
                                                   float* out,
                                                   float* __restrict__ sscr,
                                                   int nrows) {
    constexpr int CG  = M / 8;        // column groups (8 cols each)
    constexpr int RG  = 256 / CG;     // row groups
    constexpr int RPB = RG * 4;       // rows per block
    constexpr int KP  = K + 4;        // padded LDS row stride
    __shared__ __align__(16) float sW[K * M];
    __shared__ __align__(16) float sS[RPB * KP];

    const int t = threadIdx.x;
    const int row0 = blockIdx.x * RPB;

    for (int i = t; i < (K * M) / 4; i += 256)
        ((float4*)sW)[i] = ((const float4*)W)[i];

    for (int i = t; i < (RPB * K) / 4; i += 256) {
        int r = i / (K / 4), k4 = i % (K / 4);
        int gr = row0 + r;
        float4 v = make_float4(0.f, 0.f, 0.f, 0.f);
        if (gr < nrows) {
            v = ((const float4*)(A + (size_t)gr * K))[k4];
            if (A2) {
                float4 w2 = ((const float4*)(A2 + (size_t)gr * K))[k4];
                v.x += w2.x; v.y += w2.y; v.z += w2.z; v.w += w2.w;
            }
        }
        *(float4*)(sS + r * KP + k4 * 4) = v;
    }
    __syncthreads();

    const int cg = t % CG, rg = t / CG;
    float acc[4][8];
#pragma unroll
    for (int i = 0; i < 4; i++)
#pragma unroll
        for (int j = 0; j < 8; j++) acc[i][j] = 0.f;

    const float* sSr = sS + (rg * 4) * KP;
    const float4* sW4 = (const float4*)sW;
#pragma unroll 4
    for (int k = 0; k < K; k++) {
        float4 wA = sW4[k * (M / 4) + cg * 2];
        float4 wB = sW4[k * (M / 4) + cg * 2 + 1];
        float wv[8] = {wA.x, wA.y, wA.z, wA.w, wB.x, wB.y, wB.z, wB.w};
        float sv[4] = {sSr[k], sSr[KP + k], sSr[2 * KP + k], sSr[3 * KP + k]};
#pragma unroll
        for (int i = 0; i < 4; i++)
#pragma unroll
            for (int j = 0; j < 8; j++) acc[i][j] = fmaf(sv[i], wv[j], acc[i][j]);
    }

    float bv[8];
#pragma unroll
    for (int j = 0; j < 8; j++) bv[j] = bias ? bias[cg * 8 + j] : 0.f;

    float ps[8], pq[8];
#pragma unroll
    for (int j = 0; j < 8; j++) { ps[j] = 0.f; pq[j] = 0.f; }

#pragma unroll
    for (int i = 0; i < 4; i++) {
        int gr = row0 + rg * 4 + i;
        if (gr < nrows) {
            float o[8];
#pragma unroll
            for (int j = 0; j < 8; j++) {
                float v = acc[i][j] + bv[j];
                if (ACT == 1) v = fmaxf(v, 0.f);
                if (ACT == 2) v = tanhf(v);
                o[j] = v;
                ps[j] += v; pq[j] += v * v;
            }
            float4* o4 = (float4*)(out + (size_t)gr * M + cg * 8);
            o4[0] = make_float4(o[0], o[1], o[2], o[3]);
            o4[1] = make_float4(o[4], o[5], o[6], o[7]);
        }
    }

    if (STATS) {
        __syncthreads();  // done reading sS; reuse as reduction scratch
#pragma unroll
        for (int j = 0; j < 8; j++) {
            sS[rg * M + cg * 8 + j] = ps[j];
            sS[RG * M + rg * M + cg * 8 + j] = pq[j];
        }
        __syncthreads();
        if (t < M) {
            float s = 0.f, q = 0.f;
#pragma unroll
            for (int i = 0; i < RG; i++) { s += sS[i * M + t]; q += sS[RG * M + i * M + t]; }
            sscr[(size_t)blockIdx.x * 2 * M + t]     = s;
            sscr[(size_t)blockIdx.x * 2 * M + M + t] = q;
        }
    }
}

// parallel reduce: sscr[nblk][2M] -> cs[2M]; grid = 2M/8 blocks x 256 threads.
template <int M>
__global__ __launch_bounds__(256) void stats_reduce_kernel(const float* __restrict__ sscr,
                                                           int nblk,
                                                           float* __restrict__ cs) {
    const int cols = 2 * M;
    const int t = threadIdx.x;
    const int c = blockIdx.x * 8 + (t & 7);   // global column
    const int rl = t >> 3;                    // row lane 0..31
    float s = 0.f;
    for (int r = rl; r < nblk; r += 32)
        s += sscr[(size_t)r * cols + c];
    __shared__ float sh[256];
    sh[t] = s;
    __syncthreads();
#pragma unroll
    for (int st = 128; st >= 8; st >>= 1) {
        if (t < st) sh[t] += sh[t + st];
        __syncthreads();
    }
    if (t < 8) cs[c] = sh[t];
}

// ---------------- in-place batchnorm apply (stats finalized inline) ----------------
template <int NC, int RELU>
__global__ __launch_bounds__(256) void bn_apply_kernel(float* buf,
                                                       const float* __restrict__ cs,
                                                       const float* __restrict__ g,
                                                       const float* __restrict__ b) {
    int i = blockIdx.x * 256 + threadIdx.x;
    const int total4 = NND * NC / 4;
    if (i >= total4) return;
    int c = (i * 4) % NC;
    const float invN = 1.0f / (float)NND;
    float4 v = ((float4*)buf)[i];
    float o[4] = {v.x, v.y, v.z, v.w};
#pragma unroll
    for (int j = 0; j < 4; j++) {
        float mu = cs[c + j] * invN;
        float var = fmaxf(cs[NC + c + j] * invN - mu * mu, 0.f);
        float rs = rsqrtf(var + 1e-5f);
        float A = g[c + j] * rs;
        float B = b[c + j] - mu * A;
        float y = fmaf(o[j], A, B);
        if (RELU) y = fmaxf(y, 0.f);
        o[j] = y;
    }
    ((float4*)buf)[i] = make_float4(o[0], o[1], o[2], o[3]);
}

// ---------------- assignment / gumbel-softmax lambdas ----------------
__global__ __launch_bounds__(256) void assign_kernel(const float* __restrict__ a1,
                                                     const float* __restrict__ Wfc2,
                                                     const float* __restrict__ bfc2,
                                                     float* __restrict__ assn,
                                                     float* __restrict__ lam,
                                                     uint32_t kg0, uint32_t kg1) {
    __shared__ float w[DIM * 2];
    int t = threadIdx.x;
    w[t] = Wfc2[t];  // 256 threads, 256 values
    __syncthreads();
    int n = blockIdx.x * 256 + t;
    if (n >= NND) return;

    float d0 = bfc2[0], d1 = bfc2[1];
    const float4* row4 = (const float4*)(a1 + (size_t)n * DIM);
#pragma unroll 8
    for (int k4 = 0; k4 < DIM / 4; k4++) {
        float4 v = row4[k4];
        d0 = fmaf(v.x, w[8 * k4 + 0], d0); d1 = fmaf(v.x, w[8 * k4 + 1], d1);
        d0 = fmaf(v.y, w[8 * k4 + 2], d0); d1 = fmaf(v.y, w[8 * k4 + 3], d1);
        d0 = fmaf(v.z, w[8 * k4 + 4], d0); d1 = fmaf(v.z, w[8 * k4 + 5], d1);
        d0 = fmaf(v.w, w[8 * k4 + 6], d0); d1 = fmaf(v.w, w[8 * k4 + 7], d1);
    }
    float m = fmaxf(d0, d1);
    float e0 = expf(d0 - m), e1 = expf(d1 - m);
    float inv = 1.f / (e0 + e1);
    float as0 = e0 * inv, as1 = e1 * inv;
    assn[2 * n] = as0; assn[2 * n + 1] = as1;

    float uf0 = rbits_u01(kg0, kg1, (uint32_t)(2 * n));
    float uf1 = rbits_u01(kg0, kg1, (uint32_t)(2 * n + 1));
    float u0 = fmaxf(1e-10f, uf0 + 1e-10f);
    float u1 = fmaxf(1e-10f, uf1 + 1e-10f);
    float gu0 = -logf(-logf(u0));
    float gu1 = -logf(-logf(u1));
    float y0 = as0 + gu0, y1 = as1 + gu1;
    float mm = fmaxf(y0, y1);
    float f0 = expf(y0 - mm), f1 = expf(y1 - mm);
    float iv = 1.f / (f0 + f1);
    lam[2 * n] = f0 * iv; lam[2 * n + 1] = f1 * iv;
}

// ---------------- noisy features + kl partial sums (per-block, no atomics) ------
__global__ __launch_bounds__(256) void noisy_kernel(const float* __restrict__ nfeat,
                                                    const float* __restrict__ lam,
                                                    const float* __restrict__ cs3,
                                                    float* __restrict__ noisy,
                                                    float* __restrict__ kpart,
                                                    uint32_t kn0, uint32_t kn1) {
    int gt = blockIdx.x * 256 + threadIdx.x;
    int n = gt >> 5, c4 = gt & 31, d = c4 * 4;
    const float invN = 1.0f / (float)NND;
    float la0 = lam[2 * n], la1 = lam[2 * n + 1];
    float4 xv = *(const float4*)(nfeat + (size_t)n * DIM + d);
    float xa[4] = {xv.x, xv.y, xv.z, xv.w};
    float t1 = 0.f, t2 = 0.f, o[4];
#pragma unroll
    for (int j = 0; j < 4; j++) {
        float mu = cs3[d + j] * invN;
        float q = cs3[DIM + d + j];
        float var1 = fmaxf(q - (float)NND * mu * mu, 0.f) / (float)(NND - 1);
        float sd = sqrtf(var1);
        float r = rbits_u01(kn0, kn1, (uint32_t)(n * DIM + d + j));
        float nm = la0 * xa[j] + la1 * mu;
        float ns = la1 * sd;
        o[j] = fmaf(r, ns, nm);
        float inv = 1.0f / (sd + 1e-7f);
        float z1 = ns * inv;            t1 += z1 * z1;
        float z2 = (nm - mu) * inv;     t2 += z2 * z2;
    }
    *(float4*)(noisy + (size_t)n * DIM + d) = make_float4(o[0], o[1], o[2], o[3]);

    __shared__ float s1[256], s2[256];
    int t = threadIdx.x;
    s1[t] = t1; s2[t] = t2;
    __syncthreads();
    for (int s = 128; s > 0; s >>= 1) {
        if (t < s) { s1[t] += s1[t + s]; s2[t] += s2[t + s]; }
        __syncthreads();
    }
    if (t == 0) { kpart[2 * blockIdx.x] = s1[0]; kpart[2 * blockIdx.x + 1] = s2[0]; }
}

// ---------------- graph segment starts (batch is sorted) ----------------
__global__ __launch_bounds__(256) void gstart_kernel(const int* __restrict__ batch,
                                                     int* __restrict__ gstart) {
    int i = blockIdx.x * 256 + threadIdx.x;
    if (i >= NND) return;
    int b = batch[i];
    int prev = (i == 0) ? -1 : batch[i - 1];
    for (int g = prev + 1; g <= b; g++) gstart[g] = i;
    if (i == NND - 1)
        for (int g = b + 1; g <= NG; g++) gstart[g] = NND;
}

__global__ __launch_bounds__(128) void graph_emb_kernel(const float* __restrict__ noisy,
                                                        const int* __restrict__ gstart,
                                                        float* __restrict__ emb) {
    int g = blockIdx.x, c = threadIdx.x;
    int s = gstart[g], e = gstart[g + 1];
    float acc = 0.f;
    for (int r = s; r < e; r++) acc += noisy[(size_t)r * DIM + c];
    float cnt = (float)(e - s);
    emb[(size_t)g * DIM + c] = acc / fmaxf(cnt, 1.f);
}

// ---------------- proto distances + final head (one wave per graph) ----------------
__global__ __launch_bounds__(64) void head_kernel(const float* __restrict__ emb,
                                                  const float* __restrict__ protos,
                                                  const float* __restrict__ Wlast,
                                                  float* __restrict__ out_logits,
                                                  float* __restrict__ out_probs,
                                                  float* __restrict__ out_sim,
                                                  float* __restrict__ out_dist) {
    int g = blockIdx.x, l = threadIdx.x;
    float ge0 = emb[(size_t)g * DIM + l];
    float ge1 = emb[(size_t)g * DIM + l + 64];
    float gn = ge0 * ge0 + ge1 * ge1;
    float dj[10], pj[10];
#pragma unroll
    for (int j = 0; j < 10; j++) {
        float pa = protos[j * DIM + l], pb = protos[j * DIM + l + 64];
        dj[j] = ge0 * pa + ge1 * pb;
        pj[j] = pa * pa + pb * pb;
    }
    float wl0 = ge0 * Wlast[10 + l] + ge1 * Wlast[10 + l + 64];
    float wl1 = ge0 * Wlast[138 + 10 + l] + ge1 * Wlast[138 + 10 + l + 64];
#pragma unroll
    for (int s = 32; s > 0; s >>= 1) {
        gn += __shfl_xor(gn, s);
        wl0 += __shfl_xor(wl0, s);
        wl1 += __shfl_xor(wl1, s);
#pragma unroll
        for (int j = 0; j < 10; j++) {
            dj[j] += __shfl_xor(dj[j], s);
            pj[j] += __shfl_xor(pj[j], s);
        }
    }
    if (l == 0) {
        float lg0 = wl0, lg1 = wl1;
#pragma unroll
        for (int j = 0; j < 10; j++) {
            float dist = -2.f * dj[j] + gn + pj[j];
            float sv = logf((dist + 1.0f) / (dist + 1e-4f));
            out_dist[g * 10 + j] = dist;
            out_sim[g * 10 + j] = sv;
            lg0 = fmaf(Wlast[j], sv, lg0);
            lg1 = fmaf(Wlast[138 + j], sv, lg1);
        }
        out_logits[2 * g] = lg0; out_logits[2 * g + 1] = lg1;
        float m = fmaxf(lg0, lg1);
        float e0 = expf(lg0 - m), e1 = expf(lg1 - m);
        float iv = 1.f / (e0 + e1);
        out_probs[2 * g] = e0 * iv; out_probs[2 * g + 1] = e1 * iv;
    }
}

// ---------------- 2x2 adjacency accumulation (per-block partials) ----------------
__global__ __launch_bounds__(256) void adj_kernel(const float* __restrict__ assn,
                                                  const int* __restrict__ src,
                                                  const int* __restrict__ dst,
                                                  float* __restrict__ adjp) {
    int t = threadIdx.x;
    float p00 = 0.f, p01 = 0.f, p10 = 0.f, p11 = 0.f;
    for (int e = blockIdx.x * 256 + t; e < NE; e += ADJ_BLOCKS * 256) {
        float2 a = *(const float2*)(assn + 2 * (size_t)src[e]);
        float2 b = *(const float2*)(assn + 2 * (size_t)dst[e]);
        p00 += a.x * b.x; p01 += a.x * b.y; p10 += a.y * b.x; p11 += a.y * b.y;
    }
    __shared__ float s0[256], s1[256], s2[256], s3[256];
    s0[t] = p00; s1[t] = p01; s2[t] = p10; s3[t] = p11;
    __syncthreads();
    for (int s = 128; s > 0; s >>= 1) {
        if (t < s) { s0[t] += s0[t + s]; s1[t] += s1[t + s]; s2[t] += s2[t + s]; s3[t] += s3[t + s]; }
        __syncthreads();
    }
    if (t == 0) {
        float4* o = (float4*)(adjp + 4 * (size_t)blockIdx.x);
        *o = make_float4(s0[0], s1[0], s2[0], s3[0]);
    }
}

// ---------------- final scalars: reduce kl + adj partials ----------------
__global__ __launch_bounds__(256) void final_scalar_kernel(const float* __restrict__ kpart,
                                                           const float* __restrict__ adjp,
                                                           float* __restrict__ out) {
    __shared__ float sh[6 * 256];
    int t = threadIdx.x;
    float k1 = 0.f, k2 = 0.f, a0 = 0.f, a1 = 0.f, a2 = 0.f, a3 = 0.f;
    for (int i = t; i < NOISY_BLOCKS; i += 256) {
        float2 v = ((const float2*)kpart)[i];
        k1 += v.x; k2 += v.y;
    }
    for (int i = t; i < ADJ_BLOCKS; i += 256) {
        float4 v = ((const float4*)adjp)[i];
        a0 += v.x; a1 += v.y; a2 += v.z; a3 += v.w;
    }
    sh[t] = k1; sh[256 + t] = k2; sh[512 + t] = a0;
    sh[768 + t] = a1; sh[1024 + t] = a2; sh[1280 + t] = a3;
    __syncthreads();
    for (int s = 128; s > 0; s >>= 1) {
        if (t < s) {
#pragma unroll
            for (int v = 0; v < 6; v++) sh[v * 256 + t] += sh[v * 256 + t + s];
        }
        __syncthreads();
    }
    if (t == 0) {
        float kl = 0.5f / ((float)NND * (float)DIM) * sh[0] + (1.0f / (float)DIM) * sh[256];
        out[16896] = kl;
        float a00 = sh[512], a01 = sh[768], a10 = sh[1024], a11 = sh[1280];
        float r0 = fmaxf(fabsf(a00) + fabsf(a01), 1e-12f);
        float r1 = fmaxf(fabsf(a10) + fabsf(a11), 1e-12f);
        float d0 = a00 / r0 - 1.f, d1 = a11 / r1 - 1.f;
        out[16897] = 0.5f * (d0 * d0 + d1 * d1);
    }
}

// ---------------- launcher ----------------
extern "C" void kernel_launch(void* const* d_in, const int* in_sizes, int n_in,
                              void* d_out, int out_size, void* d_ws, size_t ws_size,
                              hipStream_t stream) {
    (void)in_sizes; (void)n_in; (void)out_size; (void)ws_size;
    const float* x     = (const float*)d_in[0];
    const int*   ei    = (const int*)d_in[1];
    const int*   batch = (const int*)d_in[2];
    const float* W0a   = (const float*)d_in[3];
    const float* W0b   = (const float*)d_in[4];
    const float* g0    = (const float*)d_in[5];
    const float* b0    = (const float*)d_in[6];
    const float* W1a   = (const float*)d_in[7];
    const float* W1b   = (const float*)d_in[8];
    const float* g1    = (const float*)d_in[9];
    const float* b1    = (const float*)d_in[10];
    const float* Wm0   = (const float*)d_in[11];
    const float* bm0   = (const float*)d_in[12];
    const float* gm    = (const float*)d_in[13];
    const float* bm    = (const float*)d_in[14];
    const float* Wm1   = (const float*)d_in[15];
    const float* bm1   = (const float*)d_in[16];
    const float* Wfc1  = (const float*)d_in[17];
    const float* bfc1  = (const float*)d_in[18];
    const float* Wfc2  = (const float*)d_in[19];
    const float* bfc2  = (const float*)d_in[20];
    const float* protos= (const float*)d_in[21];
    const float* Wlast = (const float*)d_in[22];
    const int* src = ei;
    const int* dst = ei + NE;
    float* out = (float*)d_out;

    float* ws   = (float*)d_ws;
    float* agg  = ws;                               // N*128
    float* tA   = agg + (size_t)NND * DIM;          // N*128
    float* t5   = tA + (size_t)NND * DIM;           // N*64
    float* lam  = t5 + (size_t)NND * HID;           // N*2
    float* assn = lam + (size_t)NND * 2;            // N*2
    float* cs   = assn + (size_t)NND * 2;           // 1024 (4 stat segments)
    float* kpart= cs + 1024;                        // NOISY_BLOCKS*2
    float* adjp = kpart + NOISY_BLOCKS * 2;         // ADJ_BLOCKS*4
    float* sscr = adjp + ADJ_BLOCKS * 4;            // 625*256 stats partials
    int* ib     = (int*)(sscr + 625 * 256);         // int region
    int* deg    = ib;                               // N
    int* offv   = deg + NND;                        // N+1
    int* cursor = offv + NND + 1;                   // N
    int* elist  = cursor + NND;                     // E
    int* gstart = elist + NE;                       // NG+1
    int* bsum   = gstart + NG + 1;                  // NSCB
    int* boff   = bsum + NSCB;                      // NSCB

    // threefry keys on host: key(42) = (0,42); partitionable fold-like split
    uint32_t kg0 = 0u, kg1 = 0u; threefry2x32(0u, 42u, kg0, kg1);  // ctr (0,0)
    uint32_t kn0 = 0u, kn1 = 1u; threefry2x32(0u, 42u, kn0, kn1);  // ctr (0,1)

    hipMemsetAsync(deg, 0, NND * sizeof(int), stream);

    // CSR (shared by both GIN layers)
    hist_kernel<<<(NE + 255) / 256, 256, 0, stream>>>(dst, deg);
    scan_bsum_kernel<<<NSCB, 256, 0, stream>>>(deg, bsum);
    scan_boff_kernel<<<1, 256, 0, stream>>>(bsum, boff, offv);
    scan_final_kernel<<<NSCB, 256, 0, stream>>>(deg, boff, offv, cursor);
    build_kernel<<<(NE + 255) / 256, 256, 0, stream>>>(src, dst, cursor, elist);

    // GIN layer 1
    gather_kernel<<<(NND * 32) / 256, 256, 0, stream>>>(x, offv, elist, agg);
    gemm_kernel<128,128,1,0><<<625, 256, 0, stream>>>(x, agg, W0a, nullptr, agg, nullptr, NND);
    gemm_kernel<128,128,1,1><<<625, 256, 0, stream>>>(agg, nullptr, W0b, nullptr, tA, sscr, NND);
    stats_reduce_kernel<128><<<32, 256, 0, stream>>>(sscr, 625, cs + 0);
    bn_apply_kernel<128,1><<<5000, 256, 0, stream>>>(tA, cs + 0, g0, b0);      // nf1

    // GIN layer 2
    gather_kernel<<<(NND * 32) / 256, 256, 0, stream>>>(tA, offv, elist, agg);
    gemm_kernel<128,128,1,0><<<625, 256, 0, stream>>>(tA, agg, W1a, nullptr, agg, nullptr, NND);
    gemm_kernel<128,128,1,1><<<625, 256, 0, stream>>>(agg, nullptr, W1b, nullptr, tA, sscr, NND);
    stats_reduce_kernel<128><<<32, 256, 0, stream>>>(sscr, 625, cs + 256);
    bn_apply_kernel<128,0><<<5000, 256, 0, stream>>>(tA, cs + 256, g1, b1);    // nf2

    // bottleneck MLP
    gemm_kernel<128,64,0,1><<<313, 256, 0, stream>>>(tA, nullptr, Wm0, bm0, t5, sscr, NND);
    stats_reduce_kernel<64><<<16, 256, 0, stream>>>(sscr, 313, cs + 512);
    bn_apply_kernel<64,1><<<2500, 256, 0, stream>>>(t5, cs + 512, gm, bm);     // h
    gemm_kernel<64,128,0,1><<<625, 256, 0, stream>>>(t5, nullptr, Wm1, bm1, agg, sscr, NND); // node_feature
    stats_reduce_kernel<128><<<32, 256, 0, stream>>>(sscr, 625, cs + 640);
    gemm_kernel<128,128,2,0><<<625, 256, 0, stream>>>(agg, nullptr, Wfc1, bfc1, tA, nullptr, NND); // a1

    // assignment + gumbel
    assign_kernel<<<(NND + 255) / 256, 256, 0, stream>>>(tA, Wfc2, bfc2, assn, lam, kg0, kg1);

    // noisy features (into tA) + kl partials
    noisy_kernel<<<NOISY_BLOCKS, 256, 0, stream>>>(agg, lam, cs + 640, tA, kpart, kn0, kn1);

    // graph pooling + head
    gstart_kernel<<<(NND + 255) / 256, 256, 0, stream>>>(batch, gstart);
    graph_emb_kernel<<<NG, 128, 0, stream>>>(tA, gstart, out + 512);
    head_kernel<<<NG, 64, 0, stream>>>(out + 512, protos, Wlast,
                                       out, out + 256, out + 16898, out + 18178);

    // penalties
    adj_kernel<<<ADJ_BLOCKS, 256, 0, stream>>>(assn, src, dst, adjp);
    final_scalar_kernel<<<1, 256, 0, stream>>>(kpart, adjp, out);
}

// Round 5
// 560.485 us; speedup vs baseline: 2.1682x; 1.1286x over previous
//
#include <hip/hip_runtime.h>
#include <stdint.h>

#define NND 40000
#define NE  640000
#define NG  128
#define DIM 128
#define HID 64
#define ADJ_BLOCKS 640
#define NOISY_BLOCKS 5000   // NND*32/256
#define NSCB ((NND + 255) / 256)   // 157 scan blocks
#define EMB_SPLIT 8

// ---------------- threefry2x32 (20 rounds), JAX-compatible ----------------
__host__ __device__ inline uint32_t rotl32(uint32_t v, uint32_t r) {
    return (v << r) | (v >> (32u - r));
}

__host__ __device__ inline void threefry2x32(uint32_t k0, uint32_t k1,
                                             uint32_t& x0, uint32_t& x1) {
    uint32_t k2 = k0 ^ k1 ^ 0x1BD11BDAu;
    x0 += k0; x1 += k1;
#define TFR(r) { x0 += x1; x1 = rotl32(x1, r); x1 ^= x0; }
    TFR(13u) TFR(15u) TFR(26u) TFR(6u)
    x0 += k1; x1 += k2 + 1u;
    TFR(17u) TFR(29u) TFR(16u) TFR(24u)
    x0 += k2; x1 += k0 + 2u;
    TFR(13u) TFR(15u) TFR(26u) TFR(6u)
    x0 += k0; x1 += k1 + 3u;
    TFR(17u) TFR(29u) TFR(16u) TFR(24u)
    x0 += k1; x1 += k2 + 4u;
    TFR(13u) TFR(15u) TFR(26u) TFR(6u)
    x0 += k2; x1 += k0 + 5u;
#undef TFR
}

// partitionable-mode random bits -> uniform [0,1)
__device__ inline float rbits_u01(uint32_t k0, uint32_t k1, uint32_t idx) {
    uint32_t x0 = 0u, x1 = idx;
    threefry2x32(k0, k1, x0, x1);
    uint32_t b = x0 ^ x1;
    return __uint_as_float((b >> 9) | 0x3f800000u) - 1.0f;
}

// ---------------- CSR build ----------------
__global__ __launch_bounds__(256) void hist_kernel(const int* __restrict__ dst,
                                                   int* __restrict__ deg) {
    int e = blockIdx.x * 256 + threadIdx.x;
    if (e < NE) atomicAdd(&deg[dst[e]], 1);
}

// hierarchical scan, step 1: per-block sums (coalesced)
__global__ __launch_bounds__(256) void scan_bsum_kernel(const int* __restrict__ deg,
                                                        int* __restrict__ bsum) {
    int t = threadIdx.x;
    int i = blockIdx.x * 256 + t;
    int v = (i < NND) ? deg[i] : 0;
    __shared__ int sh[256];
    sh[t] = v;
    __syncthreads();
#pragma unroll
    for (int s = 128; s > 0; s >>= 1) {
        if (t < s) sh[t] += sh[t + s];
        __syncthreads();
    }
    if (t == 0) bsum[blockIdx.x] = sh[0];
}

// step 2: single small block scans the 157 block sums -> exclusive block offsets
__global__ __launch_bounds__(256) void scan_boff_kernel(const int* __restrict__ bsum,
                                                        int* __restrict__ boff,
                                                        int* __restrict__ offv) {
    int t = threadIdx.x;
    int v = (t < NSCB) ? bsum[t] : 0;
    __shared__ int sh[256];
    sh[t] = v;
    __syncthreads();
    for (int d = 1; d < 256; d <<= 1) {
        int u = (t >= d) ? sh[t - d] : 0;
        __syncthreads();
        sh[t] += u;
        __syncthreads();
    }
    if (t < NSCB) boff[t] = sh[t] - v;   // exclusive
    if (t == NSCB - 1) offv[NND] = sh[t];
}

// step 3: block-local exclusive scan + block offset -> offv/cursor (coalesced)
__global__ __launch_bounds__(256) void scan_final_kernel(const int* __restrict__ deg,
                                                         const int* __restrict__ boff,
                                                         int* __restrict__ offv,
                                                         int* __restrict__ cursor) {
    int t = threadIdx.x;
    int i = blockIdx.x * 256 + t;
    int v = (i < NND) ? deg[i] : 0;
    __shared__ int sh[256];
    sh[t] = v;
    __syncthreads();
    for (int d = 1; d < 256; d <<= 1) {
        int u = (t >= d) ? sh[t - d] : 0;
        __syncthreads();
        sh[t] += u;
        __syncthreads();
    }
    int off = boff[blockIdx.x] + sh[t] - v;   // exclusive prefix
    if (i < NND) { offv[i] = off; cursor[i] = off; }
}

__global__ __launch_bounds__(256) void build_kernel(const int* __restrict__ src,
                                                    const int* __restrict__ dst,
                                                    int* __restrict__ cursor,
                                                    int* __restrict__ elist) {
    int e = blockIdx.x * 256 + threadIdx.x;
    if (e < NE) {
        int p = atomicAdd(&cursor[dst[e]], 1);
        elist[p] = src[e];
    }
}

// agg[n] = sum over in-edges of feat[src]; full overwrite (no zero-init needed)
__global__ __launch_bounds__(256) void gather_kernel(const float* __restrict__ feat,
                                                     const int* __restrict__ offv,
                                                     const int* __restrict__ elist,
                                                     float* __restrict__ agg) {
    int gt = blockIdx.x * 256 + threadIdx.x;
    int n = gt >> 5, c4 = gt & 31;
    int o0 = offv[n], o1 = offv[n + 1];
    float4 acc = make_float4(0.f, 0.f, 0.f, 0.f);
    for (int i = o0; i < o1; i++) {
        int s = elist[i];
        float4 v = *(const float4*)(feat + (size_t)s * DIM + c4 * 4);
        acc.x += v.x; acc.y += v.y; acc.z += v.z; acc.w += v.w;
    }
    *(float4*)(agg + (size_t)n * DIM + c4 * 4) = acc;
}

// ---------------- fused GEMM: out = ACT((A [+ A2]) @ W [+ bias]); optional col stats
// ACT: 0=none, 1=relu, 2=tanh.  STATS: write per-block col sum/sumsq partials to sscr.
template <int K, int M, int ACT, int STATS>
__global__ __launch_bounds__(256) void gemm_kernel(const float* __restrict__ A,
                                                   const float* A2,
                                                   const float* __restrict__ W,
                                                   const float* __restrict__ bias,
                                                   float* out,
                                                   float* __restrict__ sscr,
                                                   int nrows) {
    constexpr int CG  = M / 8;        // column groups (8 cols each)
    constexpr int RG  = 256 / CG;     // row groups
    constexpr int RPB = RG * 4;       // rows per block
    constexpr int KP  = K + 4;        // padded LDS row stride
    __shared__ __align__(16) float sW[K * M];
    __shared__ __align__(16) float sS[RPB * KP];

    const int t = threadIdx.x;
    const int row0 = blockIdx.x * RPB;

    for (int i = t; i < (K * M) / 4; i += 256)
        ((float4*)sW)[i] = ((const float4*)W)[i];

    for (int i = t; i < (RPB * K) / 4; i += 256) {
        int r = i / (K / 4), k4 = i % (K / 4);
        int gr = row0 + r;
        float4 v = make_float4(0.f, 0.f, 0.f, 0.f);
        if (gr < nrows) {
            v = ((const float4*)(A + (size_t)gr * K))[k4];
            if (A2) {
                float4 w2 = ((const float4*)(A2 + (size_t)gr * K))[k4];
                v.x += w2.x; v.y += w2.y; v.z += w2.z; v.w += w2.w;
            }
        }
        *(float4*)(sS + r * KP + k4 * 4) = v;
    }
    __syncthreads();

    const int cg = t % CG, rg = t / CG;
    float acc[4][8];
#pragma unroll
    for (int i = 0; i < 4; i++)
#pragma unroll
        for (int j = 0; j < 8; j++) acc[i][j] = 0.f;

    const float* sSr = sS + (rg * 4) * KP;
    const float4* sW4 = (const float4*)sW;
#pragma unroll 4
    for (int k = 0; k < K; k++) {
        float4 wA = sW4[k * (M / 4) + cg * 2];
        float4 wB = sW4[k * (M / 4) + cg * 2 + 1];
        float wv[8] = {wA.x, wA.y, wA.z, wA.w, wB.x, wB.y, wB.z, wB.w};
        float sv[4] = {sSr[k], sSr[KP + k], sSr[2 * KP + k], sSr[3 * KP + k]};
#pragma unroll
        for (int i = 0; i < 4; i++)
#pragma unroll
            for (int j = 0; j < 8; j++) acc[i][j] = fmaf(sv[i], wv[j], acc[i][j]);
    }

    float bv[8];
#pragma unroll
    for (int j = 0; j < 8; j++) bv[j] = bias ? bias[cg * 8 + j] : 0.f;

    float ps[8], pq[8];
#pragma unroll
    for (int j = 0; j < 8; j++) { ps[j] = 0.f; pq[j] = 0.f; }

#pragma unroll
    for (int i = 0; i < 4; i++) {
        int gr = row0 + rg * 4 + i;
        if (gr < nrows) {
            float o[8];
#pragma unroll
            for (int j = 0; j < 8; j++) {
                float v = acc[i][j] + bv[j];
                if (ACT == 1) v = fmaxf(v, 0.f);
                if (ACT == 2) v = tanhf(v);
                o[j] = v;
                ps[j] += v; pq[j] += v * v;
            }
            float4* o4 = (float4*)(out + (size_t)gr * M + cg * 8);
            o4[0] = make_float4(o[0], o[1], o[2], o[3]);
            o4[1] = make_float4(o[4], o[5], o[6], o[7]);
        }
    }

    if (STATS) {
        __syncthreads();  // done reading sS; reuse as reduction scratch
#pragma unroll
        for (int j = 0; j < 8; j++) {
            sS[rg * M + cg * 8 + j] = ps[j];
            sS[RG * M + rg * M + cg * 8 + j] = pq[j];
        }
        __syncthreads();
        if (t < M) {
            float s = 0.f, q = 0.f;
#pragma unroll
            for (int i = 0; i < RG; i++) { s += sS[i * M + t]; q += sS[RG * M + i * M + t]; }
            sscr[(size_t)blockIdx.x * 2 * M + t]     = s;
            sscr[(size_t)blockIdx.x * 2 * M + M + t] = q;
        }
    }
}

// parallel reduce: sscr[nblk][2M] -> cs[2M]; grid = 2M/8 blocks x 256 threads.
template <int M>
__global__ __launch_bounds__(256) void stats_reduce_kernel(const float* __restrict__ sscr,
                                                           int nblk,
                                                           float* __restrict__ cs) {
    const int cols = 2 * M;
    const int t = threadIdx.x;
    const int c = blockIdx.x * 8 + (t & 7);   // global column
    const int rl = t >> 3;                    // row lane 0..31
    float s = 0.f;
    for (int r = rl; r < nblk; r += 32)
        s += sscr[(size_t)r * cols + c];
    __shared__ float sh[256];
    sh[t] = s;
    __syncthreads();
#pragma unroll
    for (int st = 128; st >= 8; st >>= 1) {
        if (t < st) sh[t] += sh[t + st];
        __syncthreads();
    }
    if (t < 8) cs[c] = sh[t];
}

// ---------------- in-place batchnorm apply (stats finalized inline) ----------------
template <int NC, int RELU>
__global__ __launch_bounds__(256) void bn_apply_kernel(float* buf,
                                                       const float* __restrict__ cs,
                                                       const float* __restrict__ g,
                                                       const float* __restrict__ b) {
    int i = blockIdx.x * 256 + threadIdx.x;
    const int total4 = NND * NC / 4;
    if (i >= total4) return;
    int c = (i * 4) % NC;
    const float invN = 1.0f / (float)NND;
    float4 v = ((float4*)buf)[i];
    float o[4] = {v.x, v.y, v.z, v.w};
#pragma unroll
    for (int j = 0; j < 4; j++) {
        float mu = cs[c + j] * invN;
        float var = fmaxf(cs[NC + c + j] * invN - mu * mu, 0.f);
        float rs = rsqrtf(var + 1e-5f);
        float A = g[c + j] * rs;
        float B = b[c + j] - mu * A;
        float y = fmaf(o[j], A, B);
        if (RELU) y = fmaxf(y, 0.f);
        o[j] = y;
    }
    ((float4*)buf)[i] = make_float4(o[0], o[1], o[2], o[3]);
}

// ---------------- assignment / gumbel-softmax lambdas ----------------
__global__ __launch_bounds__(256) void assign_kernel(const float* __restrict__ a1,
                                                     const float* __restrict__ Wfc2,
                                                     const float* __restrict__ bfc2,
                                                     float* __restrict__ assn,
                                                     float* __restrict__ lam,
                                                     uint32_t kg0, uint32_t kg1) {
    __shared__ float w[DIM * 2];
    int t = threadIdx.x;
    w[t] = Wfc2[t];  // 256 threads, 256 values
    __syncthreads();
    int n = blockIdx.x * 256 + t;
    if (n >= NND) return;

    float d0 = bfc2[0], d1 = bfc2[1];
    const float4* row4 = (const float4*)(a1 + (size_t)n * DIM);
#pragma unroll 8
    for (int k4 = 0; k4 < DIM / 4; k4++) {
        float4 v = row4[k4];
        d0 = fmaf(v.x, w[8 * k4 + 0], d0); d1 = fmaf(v.x, w[8 * k4 + 1], d1);
        d0 = fmaf(v.y, w[8 * k4 + 2], d0); d1 = fmaf(v.y, w[8 * k4 + 3], d1);
        d0 = fmaf(v.z, w[8 * k4 + 4], d0); d1 = fmaf(v.z, w[8 * k4 + 5], d1);
        d0 = fmaf(v.w, w[8 * k4 + 6], d0); d1 = fmaf(v.w, w[8 * k4 + 7], d1);
    }
    float m = fmaxf(d0, d1);
    float e0 = expf(d0 - m), e1 = expf(d1 - m);
    float inv = 1.f / (e0 + e1);
    float as0 = e0 * inv, as1 = e1 * inv;
    assn[2 * n] = as0; assn[2 * n + 1] = as1;

    float uf0 = rbits_u01(kg0, kg1, (uint32_t)(2 * n));
    float uf1 = rbits_u01(kg0, kg1, (uint32_t)(2 * n + 1));
    float u0 = fmaxf(1e-10f, uf0 + 1e-10f);
    float u1 = fmaxf(1e-10f, uf1 + 1e-10f);
    float gu0 = -logf(-logf(u0));
    float gu1 = -logf(-logf(u1));
    float y0 = as0 + gu0, y1 = as1 + gu1;
    float mm = fmaxf(y0, y1);
    float f0 = expf(y0 - mm), f1 = expf(y1 - mm);
    float iv = 1.f / (f0 + f1);
    lam[2 * n] = f0 * iv; lam[2 * n + 1] = f1 * iv;
}

// ---------------- noisy features + kl partial sums (per-block, no atomics) ------
__global__ __launch_bounds__(256) void noisy_kernel(const float* __restrict__ nfeat,
                                                    const float* __restrict__ lam,
                                                    const float* __restrict__ cs3,
                                                    float* __restrict__ noisy,
                                                    float* __restrict__ kpart,
                                                    uint32_t kn0, uint32_t kn1) {
    int gt = blockIdx.x * 256 + threadIdx.x;
    int n = gt >> 5, c4 = gt & 31, d = c4 * 4;
    const float invN = 1.0f / (float)NND;
    float la0 = lam[2 * n], la1 = lam[2 * n + 1];
    float4 xv = *(const float4*)(nfeat + (size_t)n * DIM + d);
    float xa[4] = {xv.x, xv.y, xv.z, xv.w};
    float t1 = 0.f, t2 = 0.f, o[4];
#pragma unroll
    for (int j = 0; j < 4; j++) {
        float mu = cs3[d + j] * invN;
        float q = cs3[DIM + d + j];
        float var1 = fmaxf(q - (float)NND * mu * mu, 0.f) / (float)(NND - 1);
        float sd = sqrtf(var1);
        float r = rbits_u01(kn0, kn1, (uint32_t)(n * DIM + d + j));
        float nm = la0 * xa[j] + la1 * mu;
        float ns = la1 * sd;
        o[j] = fmaf(r, ns, nm);
        float inv = 1.0f / (sd + 1e-7f);
        float z1 = ns * inv;            t1 += z1 * z1;
        float z2 = (nm - mu) * inv;     t2 += z2 * z2;
    }
    *(float4*)(noisy + (size_t)n * DIM + d) = make_float4(o[0], o[1], o[2], o[3]);

    __shared__ float s1[256], s2[256];
    int t = threadIdx.x;
    s1[t] = t1; s2[t] = t2;
    __syncthreads();
    for (int s = 128; s > 0; s >>= 1) {
        if (t < s) { s1[t] += s1[t + s]; s2[t] += s2[t + s]; }
        __syncthreads();
    }
    if (t == 0) { kpart[2 * blockIdx.x] = s1[0]; kpart[2 * blockIdx.x + 1] = s2[0]; }
}

// ---------------- graph segment starts (batch is sorted) ----------------
__global__ __launch_bounds__(256) void gstart_kernel(const int* __restrict__ batch,
                                                     int* __restrict__ gstart) {
    int i = blockIdx.x * 256 + threadIdx.x;
    if (i >= NND) return;
    int b = batch[i];
    int prev = (i == 0) ? -1 : batch[i - 1];
    for (int g = prev + 1; g <= b; g++) gstart[g] = i;
    if (i == NND - 1)
        for (int g = b + 1; g <= NG; g++) gstart[g] = NND;
}

// ---------------- graph mean pooling: split each graph across EMB_SPLIT blocks ----
__global__ __launch_bounds__(128) void graph_emb_part_kernel(const float* __restrict__ noisy,
                                                             const int* __restrict__ gstart,
                                                             float* __restrict__ gpart) {
    int g = blockIdx.x / EMB_SPLIT;
    int sidx = blockIdx.x % EMB_SPLIT;
    int c = threadIdx.x;
    int s = gstart[g], e = gstart[g + 1];
    int len = e - s;
    int chunk = (len + EMB_SPLIT - 1) / EMB_SPLIT;
    int r0 = s + sidx * chunk;
    int r1 = min(r0 + chunk, e);
    float acc = 0.f;
    for (int r = r0; r < r1; r++) acc += noisy[(size_t)r * DIM + c];
    gpart[((size_t)g * EMB_SPLIT + sidx) * DIM + c] = acc;
}

__global__ __launch_bounds__(128) void graph_emb_reduce_kernel(const float* __restrict__ gpart,
                                                               const int* __restrict__ gstart,
                                                               float* __restrict__ emb) {
    int g = blockIdx.x, c = threadIdx.x;
    float acc = 0.f;
#pragma unroll
    for (int si = 0; si < EMB_SPLIT; si++)
        acc += gpart[((size_t)g * EMB_SPLIT + si) * DIM + c];
    float cnt = (float)(gstart[g + 1] - gstart[g]);
    emb[(size_t)g * DIM + c] = acc / fmaxf(cnt, 1.f);
}

// ---------------- proto distances + final head (one wave per graph) ----------------
__global__ __launch_bounds__(64) void head_kernel(const float* __restrict__ emb,
                                                  const float* __restrict__ protos,
                                                  const float* __restrict__ Wlast,
                                                  float* __restrict__ out_logits,
                                                  float* __restrict__ out_probs,
                                                  float* __restrict__ out_sim,
                                                  float* __restrict__ out_dist) {
    int g = blockIdx.x, l = threadIdx.x;
    float ge0 = emb[(size_t)g * DIM + l];
    float ge1 = emb[(size_t)g * DIM + l + 64];
    float gn = ge0 * ge0 + ge1 * ge1;
    float dj[10], pj[10];
#pragma unroll
    for (int j = 0; j < 10; j++) {
        float pa = protos[j * DIM + l], pb = protos[j * DIM + l + 64];
        dj[j] = ge0 * pa + ge1 * pb;
        pj[j] = pa * pa + pb * pb;
    }
    float wl0 = ge0 * Wlast[10 + l] + ge1 * Wlast[10 + l + 64];
    float wl1 = ge0 * Wlast[138 + 10 + l] + ge1 * Wlast[138 + 10 + l + 64];
#pragma unroll
    for (int s = 32; s > 0; s >>= 1) {
        gn += __shfl_xor(gn, s);
        wl0 += __shfl_xor(wl0, s);
        wl1 += __shfl_xor(wl1, s);
#pragma unroll
        for (int j = 0; j < 10; j++) {
            dj[j] += __shfl_xor(dj[j], s);
            pj[j] += __shfl_xor(pj[j], s);
        }
    }
    if (l == 0) {
        float lg0 = wl0, lg1 = wl1;
#pragma unroll
        for (int j = 0; j < 10; j++) {
            float dist = -2.f * dj[j] + gn + pj[j];
            float sv = logf((dist + 1.0f) / (dist + 1e-4f));
            out_dist[g * 10 + j] = dist;
            out_sim[g * 10 + j] = sv;
            lg0 = fmaf(Wlast[j], sv, lg0);
            lg1 = fmaf(Wlast[138 + j], sv, lg1);
        }
        out_logits[2 * g] = lg0; out_logits[2 * g + 1] = lg1;
        float m = fmaxf(lg0, lg1);
        float e0 = expf(lg0 - m), e1 = expf(lg1 - m);
        float iv = 1.f / (e0 + e1);
        out_probs[2 * g] = e0 * iv; out_probs[2 * g + 1] = e1 * iv;
    }
}

// ---------------- 2x2 adjacency accumulation (per-block partials) ----------------
__global__ __launch_bounds__(256) void adj_kernel(const float* __restrict__ assn,
                                                  const int* __restrict__ src,
                                                  const int* __restrict__ dst,
                                                  float* __restrict__ adjp) {
    int t = threadIdx.x;
    float p00 = 0.f, p01 = 0.f, p10 = 0.f, p11 = 0.f;
    for (int e = blockIdx.x * 256 + t; e < NE; e += ADJ_BLOCKS * 256) {
        float2 a = *(const float2*)(assn + 2 * (size_t)src[e]);
        float2 b = *(const float2*)(assn + 2 * (size_t)dst[e]);
        p00 += a.x * b.x; p01 += a.x * b.y; p10 += a.y * b.x; p11 += a.y * b.y;
    }
    __shared__ float s0[256], s1[256], s2[256], s3[256];
    s0[t] = p00; s1[t] = p01; s2[t] = p10; s3[t] = p11;
    __syncthreads();
    for (int s = 128; s > 0; s >>= 1) {
        if (t < s) { s0[t] += s0[t + s]; s1[t] += s1[t + s]; s2[t] += s2[t + s]; s3[t] += s3[t + s]; }
        __syncthreads();
    }
    if (t == 0) {
        float4* o = (float4*)(adjp + 4 * (size_t)blockIdx.x);
        *o = make_float4(s0[0], s1[0], s2[0], s3[0]);
    }
}

// ---------------- final scalars: reduce kl + adj partials ----------------
__global__ __launch_bounds__(256) void final_scalar_kernel(const float* __restrict__ kpart,
                                                           const float* __restrict__ adjp,
                                                           float* __restrict__ out) {
    __shared__ float sh[6 * 256];
    int t = threadIdx.x;
    float k1 = 0.f, k2 = 0.f, a0 = 0.f, a1 = 0.f, a2 = 0.f, a3 = 0.f;
    for (int i = t; i < NOISY_BLOCKS; i += 256) {
        float2 v = ((const float2*)kpart)[i];
        k1 += v.x; k2 += v.y;
    }
    for (int i = t; i < ADJ_BLOCKS; i += 256) {
        float4 v = ((const float4*)adjp)[i];
        a0 += v.x; a1 += v.y; a2 += v.z; a3 += v.w;
    }
    sh[t] = k1; sh[256 + t] = k2; sh[512 + t] = a0;
    sh[768 + t] = a1; sh[1024 + t] = a2; sh[1280 + t] = a3;
    __syncthreads();
    for (int s = 128; s > 0; s >>= 1) {
        if (t < s) {
#pragma unroll
            for (int v = 0; v < 6; v++) sh[v * 256 + t] += sh[v * 256 + t + s];
        }
        __syncthreads();
    }
    if (t == 0) {
        float kl = 0.5f / ((float)NND * (float)DIM) * sh[0] + (1.0f / (float)DIM) * sh[256];
        out[16896] = kl;
        float a00 = sh[512], a01 = sh[768], a10 = sh[1024], a11 = sh[1280];
        float r0 = fmaxf(fabsf(a00) + fabsf(a01), 1e-12f);
        float r1 = fmaxf(fabsf(a10) + fabsf(a11), 1e-12f);
        float d0 = a00 / r0 - 1.f, d1 = a11 / r1 - 1.f;
        out[16897] = 0.5f * (d0 * d0 + d1 * d1);
    }
}

// ---------------- launcher ----------------
extern "C" void kernel_launch(void* const* d_in, const int* in_sizes, int n_in,
                              void* d_out, int out_size, void* d_ws, size_t ws_size,
                              hipStream_t stream) {
    (void)in_sizes; (void)n_in; (void)out_size; (void)ws_size;
    const float* x     = (const float*)d_in[0];
    const int*   ei    = (const int*)d_in[1];
    const int*   batch = (const int*)d_in[2];
    const float* W0a   = (const float*)d_in[3];
    const float* W0b   = (const float*)d_in[4];
    const float* g0    = (const float*)d_in[5];
    const float* b0    = (const float*)d_in[6];
    const float* W1a   = (const float*)d_in[7];
    const float* W1b   = (const float*)d_in[8];
    const float* g1    = (const float*)d_in[9];
    const float* b1    = (const float*)d_in[10];
    const float* Wm0   = (const float*)d_in[11];
    const float* bm0   = (const float*)d_in[12];
    const float* gm    = (const float*)d_in[13];
    const float* bm    = (const float*)d_in[14];
    const float* Wm1   = (const float*)d_in[15];
    const float* bm1   = (const float*)d_in[16];
    const float* Wfc1  = (const float*)d_in[17];
    const float* bfc1  = (const float*)d_in[18];
    const float* Wfc2  = (const float*)d_in[19];
    const float* bfc2  = (const float*)d_in[20];
    const float* protos= (const float*)d_in[21];
    const float* Wlast = (const float*)d_in[22];
    const int* src = ei;
    const int* dst = ei + NE;
    float* out = (float*)d_out;

    float* ws   = (float*)d_ws;
    float* agg  = ws;                               // N*128
    float* tA   = agg + (size_t)NND * DIM;          // N*128
    float* t5   = tA + (size_t)NND * DIM;           // N*64
    float* lam  = t5 + (size_t)NND * HID;           // N*2
    float* assn = lam + (size_t)NND * 2;            // N*2
    float* cs   = assn + (size_t)NND * 2;           // 1024 (4 stat segments)
    float* kpart= cs + 1024;                        // NOISY_BLOCKS*2
    float* adjp = kpart + NOISY_BLOCKS * 2;         // ADJ_BLOCKS*4
    float* sscr = adjp + ADJ_BLOCKS * 4;            // 625*256 stats partials
    float* gpart= sscr + 625 * 256;                 // NG*EMB_SPLIT*DIM
    int* ib     = (int*)(gpart + NG * EMB_SPLIT * DIM);  // int region
    int* deg    = ib;                               // N
    int* offv   = deg + NND;                        // N+1
    int* cursor = offv + NND + 1;                   // N
    int* elist  = cursor + NND;                     // E
    int* gstart = elist + NE;                       // NG+1
    int* bsum   = gstart + NG + 1;                  // NSCB
    int* boff   = bsum + NSCB;                      // NSCB

    // threefry keys on host: key(42) = (0,42); partitionable fold-like split
    uint32_t kg0 = 0u, kg1 = 0u; threefry2x32(0u, 42u, kg0, kg1);  // ctr (0,0)
    uint32_t kn0 = 0u, kn1 = 1u; threefry2x32(0u, 42u, kn0, kn1);  // ctr (0,1)

    hipMemsetAsync(deg, 0, NND * sizeof(int), stream);

    // CSR (shared by both GIN layers)
    hist_kernel<<<(NE + 255) / 256, 256, 0, stream>>>(dst, deg);
    scan_bsum_kernel<<<NSCB, 256, 0, stream>>>(deg, bsum);
    scan_boff_kernel<<<1, 256, 0, stream>>>(bsum, boff, offv);
    scan_final_kernel<<<NSCB, 256, 0, stream>>>(deg, boff, offv, cursor);
    build_kernel<<<(NE + 255) / 256, 256, 0, stream>>>(src, dst, cursor, elist);

    // GIN layer 1
    gather_kernel<<<(NND * 32) / 256, 256, 0, stream>>>(x, offv, elist, agg);
    gemm_kernel<128,128,1,0><<<625, 256, 0, stream>>>(x, agg, W0a, nullptr, agg, nullptr, NND);
    gemm_kernel<128,128,1,1><<<625, 256, 0, stream>>>(agg, nullptr, W0b, nullptr, tA, sscr, NND);
    stats_reduce_kernel<128><<<32, 256, 0, stream>>>(sscr, 625, cs + 0);
    bn_apply_kernel<128,1><<<5000, 256, 0, stream>>>(tA, cs + 0, g0, b0);      // nf1

    // GIN layer 2
    gather_kernel<<<(NND * 32) / 256, 256, 0, stream>>>(tA, offv, elist, agg);
    gemm_kernel<128,128,1,0><<<625, 256, 0, stream>>>(tA, agg, W1a, nullptr, agg, nullptr, NND);
    gemm_kernel<128,128,1,1><<<625, 256, 0, stream>>>(agg, nullptr, W1b, nullptr, tA, sscr, NND);
    stats_reduce_kernel<128><<<32, 256, 0, stream>>>(sscr, 625, cs + 256);
    bn_apply_kernel<128,0><<<5000, 256, 0, stream>>>(tA, cs + 256, g1, b1);    // nf2

    // bottleneck MLP
    gemm_kernel<128,64,0,1><<<313, 256, 0, stream>>>(tA, nullptr, Wm0, bm0, t5, sscr, NND);
    stats_reduce_kernel<64><<<16, 256, 0, stream>>>(sscr, 313, cs + 512);
    bn_apply_kernel<64,1><<<2500, 256, 0, stream>>>(t5, cs + 512, gm, bm);     // h
    gemm_kernel<64,128,0,1><<<625, 256, 0, stream>>>(t5, nullptr, Wm1, bm1, agg, sscr, NND); // node_feature
    stats_reduce_kernel<128><<<32, 256, 0, stream>>>(sscr, 625, cs + 640);
    gemm_kernel<128,128,2,0><<<625, 256, 0, stream>>>(agg, nullptr, Wfc1, bfc1, tA, nullptr, NND); // a1

    // assignment + gumbel
    assign_kernel<<<(NND + 255) / 256, 256, 0, stream>>>(tA, Wfc2, bfc2, assn, lam, kg0, kg1);

    // noisy features (into tA) + kl partials
    noisy_kernel<<<NOISY_BLOCKS, 256, 0, stream>>>(agg, lam, cs + 640, tA, kpart, kn0, kn1);

    // graph pooling + head
    gstart_kernel<<<(NND + 255) / 256, 256, 0, stream>>>(batch, gstart);
    graph_emb_part_kernel<<<NG * EMB_SPLIT, 128, 0, stream>>>(tA, gstart, gpart);
    graph_emb_reduce_kernel<<<NG, 128, 0, stream>>>(gpart, gstart, out + 512);
    head_kernel<<<NG, 64, 0, stream>>>(out + 512, protos, Wlast,
                                       out, out + 256, out + 16898, out + 18178);

    // penalties
    adj_kernel<<<ADJ_BLOCKS, 256, 0, stream>>>(assn, src, dst, adjp);
    final_scalar_kernel<<<1, 256, 0, stream>>>(kpart, adjp, out);
}